// Round 3
// baseline (1165.509 us; speedup 1.0000x reference)
//
#include <hip/hip_runtime.h>
#include <math.h>

#define EPSV 1e-5f

__device__ __forceinline__ float gelu_f(float x) {
    return 0.5f * x * (1.0f + erff(x * 0.70710678118654752440f));
}

// ---------------- degree / dinv ----------------
__global__ void deg_kernel(const int* __restrict__ ei, int* __restrict__ deg, int E) {
    int stride = gridDim.x * blockDim.x;
    for (int e = blockIdx.x * blockDim.x + threadIdx.x; e < E; e += stride)
        atomicAdd(&deg[ei[E + e]], 1);   // dst occurrences
}

__global__ void dinv_kernel(const int* __restrict__ deg, float* __restrict__ dinv, int N) {
    int i = blockIdx.x * blockDim.x + threadIdx.x;
    if (i < N) dinv[i] = rsqrtf((float)(deg[i] + 1));  // +1 self loop
}

// ---------------- exclusive scan of deg -> off  (single block, 1024 threads) ----------------
__global__ __launch_bounds__(1024) void scan_kernel(const int* __restrict__ deg,
                                                    int* __restrict__ off, int N) {
    __shared__ int sh[1024];
    int t = threadIdx.x;
    int chunk = (N + 1023) >> 10;
    int b = t * chunk;
    int e = b + chunk; if (e > N) e = N;
    int s = 0;
    for (int i = b; i < e; ++i) s += deg[i];
    sh[t] = s;
    __syncthreads();
    for (int d = 1; d < 1024; d <<= 1) {
        int v = (t >= d) ? sh[t - d] : 0;
        __syncthreads();
        sh[t] += v;
        __syncthreads();
    }
    int run = (t > 0) ? sh[t - 1] : 0;
    for (int i = b; i < e; ++i) { off[i] = run; run += deg[i]; }
    if (t == 1023) off[N] = sh[1023];
}

// ---------------- CSR fill: csr[off[d] + rank] = src ----------------
__global__ void fill_kernel(const int* __restrict__ ei, const int* __restrict__ off,
                            int* __restrict__ fill, int* __restrict__ csr, int E) {
    int stride = gridDim.x * blockDim.x;
    for (int e = blockIdx.x * blockDim.x + threadIdx.x; e < E; e += stride) {
        int d = ei[E + e];
        int p = off[d] + atomicAdd(&fill[d], 1);
        csr[p] = ei[e];
    }
}

// ---------------- GEMM: C[i][c] = (sum_k A[i][k] W[k][c]) * dinv[i] ----------------
// 64x64 tile, BK=16, 256 threads, 4x4 micro-tile per thread.
__global__ __launch_bounds__(256) void gemm_scale_kernel(
    const float* __restrict__ A, const float* __restrict__ W,
    const float* __restrict__ dinv, float* __restrict__ C,
    int M, int K, int Nc)
{
    __shared__ float As[64][17];
    __shared__ float4 Ws4[16][16];
    const int tid = threadIdx.x;
    const int tx = tid & 15, ty = tid >> 4;
    const int row0 = blockIdx.y * 64, col0 = blockIdx.x * 64;
    float acc[4][4] = {};
    const int ar = tid >> 2, ac4 = (tid & 3) * 4;   // A-tile coords
    const int wr = tid >> 4, wc4 = (tid & 15) * 4;  // W-tile coords

    for (int kk = 0; kk < K; kk += 16) {
        float4 av = make_float4(0.f, 0.f, 0.f, 0.f);
        int grow = row0 + ar;
        if (grow < M) av = *(const float4*)(A + (long)grow * K + kk + ac4);
        As[ar][ac4 + 0] = av.x; As[ar][ac4 + 1] = av.y;
        As[ar][ac4 + 2] = av.z; As[ar][ac4 + 3] = av.w;
        Ws4[wr][tid & 15] = *(const float4*)(W + (long)(kk + wr) * Nc + col0 + wc4);
        __syncthreads();
#pragma unroll
        for (int k = 0; k < 16; ++k) {
            float4 b4 = Ws4[k][tx];
            float a0 = As[ty * 4 + 0][k];
            float a1 = As[ty * 4 + 1][k];
            float a2 = As[ty * 4 + 2][k];
            float a3 = As[ty * 4 + 3][k];
            acc[0][0] = fmaf(a0, b4.x, acc[0][0]); acc[0][1] = fmaf(a0, b4.y, acc[0][1]);
            acc[0][2] = fmaf(a0, b4.z, acc[0][2]); acc[0][3] = fmaf(a0, b4.w, acc[0][3]);
            acc[1][0] = fmaf(a1, b4.x, acc[1][0]); acc[1][1] = fmaf(a1, b4.y, acc[1][1]);
            acc[1][2] = fmaf(a1, b4.z, acc[1][2]); acc[1][3] = fmaf(a1, b4.w, acc[1][3]);
            acc[2][0] = fmaf(a2, b4.x, acc[2][0]); acc[2][1] = fmaf(a2, b4.y, acc[2][1]);
            acc[2][2] = fmaf(a2, b4.z, acc[2][2]); acc[2][3] = fmaf(a2, b4.w, acc[2][3]);
            acc[3][0] = fmaf(a3, b4.x, acc[3][0]); acc[3][1] = fmaf(a3, b4.y, acc[3][1]);
            acc[3][2] = fmaf(a3, b4.z, acc[3][2]); acc[3][3] = fmaf(a3, b4.w, acc[3][3]);
        }
        __syncthreads();
    }
#pragma unroll
    for (int i = 0; i < 4; ++i) {
        int grow = row0 + ty * 4 + i;
        if (grow < M) {
            float dv = dinv[grow];
            float4 o = make_float4(acc[i][0] * dv, acc[i][1] * dv, acc[i][2] * dv, acc[i][3] * dv);
            *(float4*)(C + (long)grow * Nc + col0 + tx * 4) = o;
        }
    }
}

// ---------------- gather: t[d] = dinv[d]*(hs[d] + sum_{s in CSR[d]} hs[s]) + b
//                  4-way edge unroll (4 rows in flight), fused column stats ----------------
template<int F>
__global__ __launch_bounds__(256) void gather_kernel(
    const float* __restrict__ hs, const int* __restrict__ off,
    const int* __restrict__ csr, const float* __restrict__ dinv,
    const float* __restrict__ bias, float* __restrict__ t,
    float* __restrict__ cs1, float* __restrict__ cs2, int N)
{
    constexpr int LPN = F / 4;        // float4 lanes per node row
    constexpr int NPB = 256 / LPN;    // node slots per block
    const int lane = threadIdx.x % LPN;
    const int slot = threadIdx.x / LPN;
    const float4* hs4 = (const float4*)hs;
    float4* t4 = (float4*)t;
    const float4 bv = ((const float4*)bias)[lane];

    float4 a1 = make_float4(0.f, 0.f, 0.f, 0.f);
    float4 a2 = make_float4(0.f, 0.f, 0.f, 0.f);

    for (int d = blockIdx.x * NPB + slot; d < N; d += gridDim.x * NPB) {
        float4 acc0 = hs4[(long)d * LPN + lane];   // self loop
        float4 acc1 = make_float4(0.f, 0.f, 0.f, 0.f);
        float4 acc2 = make_float4(0.f, 0.f, 0.f, 0.f);
        float4 acc3 = make_float4(0.f, 0.f, 0.f, 0.f);
        const int e0 = off[d], e1 = off[d + 1];
        int e = e0;
        for (; e + 4 <= e1; e += 4) {
            int s0 = csr[e + 0];
            int s1 = csr[e + 1];
            int s2 = csr[e + 2];
            int s3 = csr[e + 3];
            float4 v0 = hs4[(long)s0 * LPN + lane];
            float4 v1 = hs4[(long)s1 * LPN + lane];
            float4 v2 = hs4[(long)s2 * LPN + lane];
            float4 v3 = hs4[(long)s3 * LPN + lane];
            acc0.x += v0.x; acc0.y += v0.y; acc0.z += v0.z; acc0.w += v0.w;
            acc1.x += v1.x; acc1.y += v1.y; acc1.z += v1.z; acc1.w += v1.w;
            acc2.x += v2.x; acc2.y += v2.y; acc2.z += v2.z; acc2.w += v2.w;
            acc3.x += v3.x; acc3.y += v3.y; acc3.z += v3.z; acc3.w += v3.w;
        }
        for (; e < e1; ++e) {
            int s = csr[e];
            float4 v = hs4[(long)s * LPN + lane];
            acc0.x += v.x; acc0.y += v.y; acc0.z += v.z; acc0.w += v.w;
        }
        acc0.x += acc1.x + acc2.x + acc3.x;
        acc0.y += acc1.y + acc2.y + acc3.y;
        acc0.z += acc1.z + acc2.z + acc3.z;
        acc0.w += acc1.w + acc2.w + acc3.w;

        float dv = dinv[d];
        float4 o;
        o.x = fmaf(dv, acc0.x, bv.x);
        o.y = fmaf(dv, acc0.y, bv.y);
        o.z = fmaf(dv, acc0.z, bv.z);
        o.w = fmaf(dv, acc0.w, bv.w);
        t4[(long)d * LPN + lane] = o;
        a1.x += o.x; a1.y += o.y; a1.z += o.z; a1.w += o.w;
        a2.x += o.x * o.x; a2.y += o.y * o.y; a2.z += o.z * o.z; a2.w += o.w * o.w;
    }

    // reduce stats across node slots (same feature lane), then one atomic set per block
    __shared__ float red[8][256];
    red[0][threadIdx.x] = a1.x; red[1][threadIdx.x] = a1.y;
    red[2][threadIdx.x] = a1.z; red[3][threadIdx.x] = a1.w;
    red[4][threadIdx.x] = a2.x; red[5][threadIdx.x] = a2.y;
    red[6][threadIdx.x] = a2.z; red[7][threadIdx.x] = a2.w;
    __syncthreads();
    if (slot == 0) {
#pragma unroll
        for (int k = 0; k < 8; ++k) {
            float s = 0.f;
            for (int j = 0; j < NPB; ++j) s += red[k][j * LPN + lane];
            if (k < 4) atomicAdd(&cs1[lane * 4 + k], s);
            else       atomicAdd(&cs2[lane * 4 + (k - 4)], s);
        }
    }
}

// ---------------- mean / istd per column ----------------
__global__ void statfinal_kernel(const float* __restrict__ s1, const float* __restrict__ s2,
                                 const float* __restrict__ ga,
                                 float* __restrict__ meanv, float* __restrict__ istdv,
                                 int M, int fout)
{
    int c = threadIdx.x;
    if (c < fout) {
        float m = s1[c] / (float)M;
        float a = ga[c];
        float var = s2[c] / (float)M - 2.f * a * m * m + a * a * m * m;
        meanv[c] = m;
        istdv[c] = rsqrtf(var + EPSV);
    }
}

// ---------------- graphnorm + gelu (+ residual) ----------------
__global__ __launch_bounds__(256) void normgelu_kernel(
    const float* __restrict__ t, const float* __restrict__ meanv,
    const float* __restrict__ istdv, const float* __restrict__ gw,
    const float* __restrict__ gb, const float* __restrict__ ga,
    const float* __restrict__ res, float* __restrict__ out,
    int log2f, long total)
{
    long stride = (long)gridDim.x * blockDim.x;
    int fmask = (1 << log2f) - 1;
    for (long idx = (long)blockIdx.x * blockDim.x + threadIdx.x; idx < total; idx += stride) {
        int c = (int)idx & fmask;
        float v = t[idx];
        float y = gw[c] * (v - ga[c] * meanv[c]) * istdv[c] + gb[c];
        y = gelu_f(y);
        if (res) y += res[idx];
        out[idx] = y;
    }
}

// ---------------- pooling (fout = 64) ----------------
__device__ __forceinline__ void atomicMaxFloat(float* addr, float val) {
    unsigned* ua = (unsigned*)addr;
    unsigned old = *ua;
    while (true) {
        float of = __uint_as_float(old);
        if (of >= val) break;
        unsigned assumed = old;
        old = atomicCAS(ua, assumed, __float_as_uint(val));
        if (old == assumed) break;
    }
}

__global__ void initpool_kernel(float* __restrict__ psum, float* __restrict__ pmax) {
    int t = threadIdx.x;
    psum[t] = 0.f;
    pmax[t] = -INFINITY;
}

__global__ __launch_bounds__(256) void colpool_kernel(
    const float* __restrict__ x, float* __restrict__ psum, float* __restrict__ pmax,
    int M, int rowsPerBlock)
{
    int c = threadIdx.x & 63;
    int rl = threadIdx.x >> 6;
    int r0 = blockIdx.x * rowsPerBlock;
    int rend = r0 + rowsPerBlock; if (rend > M) rend = M;
    float a1 = 0.f, am = -INFINITY;
    for (int r = r0 + rl; r < rend; r += 4) {
        float v = x[(long)r * 64 + c];
        a1 += v; am = fmaxf(am, v);
    }
    __shared__ float sh1[256], shm[256];
    sh1[threadIdx.x] = a1; shm[threadIdx.x] = am;
    __syncthreads();
    if (threadIdx.x < 64) {
        for (int j = 1; j < 4; ++j) {
            a1 += sh1[c + j * 64];
            am = fmaxf(am, shm[c + j * 64]);
        }
        atomicAdd(&psum[c], a1);
        atomicMaxFloat(&pmax[c], am);
    }
}

// ---------------- head: pooled -> linear -> layernorm -> gelu -> linear ----------------
__global__ void head_kernel(const float* __restrict__ psum, const float* __restrict__ pmax,
                            const float* __restrict__ wc1, const float* __restrict__ bc1,
                            const float* __restrict__ lnw, const float* __restrict__ lnb,
                            const float* __restrict__ wc2, const float* __restrict__ bc2,
                            float* __restrict__ out, int M)
{
    __shared__ float p[192];
    int t = threadIdx.x; // 64 threads = 1 wave
    float s = psum[t];
    p[t] = s / (float)M;
    p[64 + t] = pmax[t];
    p[128 + t] = s;
    __syncthreads();
    float h = bc1[t];
    for (int k = 0; k < 192; ++k) h = fmaf(p[k], wc1[k * 64 + t], h);
    float m = h;
    for (int off = 32; off > 0; off >>= 1) m += __shfl_xor(m, off);
    m *= (1.f / 64.f);
    float d = h - m;
    float v = d * d;
    for (int off = 32; off > 0; off >>= 1) v += __shfl_xor(v, off);
    v *= (1.f / 64.f);
    float y = d * rsqrtf(v + EPSV) * lnw[t] + lnb[t];
    y = gelu_f(y);
    float o0 = y * wc2[t * 2 + 0];
    float o1 = y * wc2[t * 2 + 1];
    for (int off = 32; off > 0; off >>= 1) {
        o0 += __shfl_xor(o0, off);
        o1 += __shfl_xor(o1, off);
    }
    if (t == 0) {
        out[0] = o0 + bc2[0];
        out[1] = o1 + bc2[1];
    }
}

extern "C" void kernel_launch(void* const* d_in, const int* in_sizes, int n_in,
                              void* d_out, int out_size, void* d_ws, size_t ws_size,
                              hipStream_t stream)
{
    const float* x    = (const float*)d_in[0];
    const int*   ei   = (const int*)d_in[1];
    const float* w0   = (const float*)d_in[2];
    const float* b0   = (const float*)d_in[3];
    const float* gn0w = (const float*)d_in[4];
    const float* gn0b = (const float*)d_in[5];
    const float* gn0a = (const float*)d_in[6];
    const float* w1   = (const float*)d_in[7];
    const float* b1   = (const float*)d_in[8];
    const float* gn1w = (const float*)d_in[9];
    const float* gn1b = (const float*)d_in[10];
    const float* gn1a = (const float*)d_in[11];
    const float* w2   = (const float*)d_in[12];
    const float* b2   = (const float*)d_in[13];
    const float* gn2w = (const float*)d_in[14];
    const float* gn2b = (const float*)d_in[15];
    const float* gn2a = (const float*)d_in[16];
    const float* wc1  = (const float*)d_in[17];
    const float* bc1  = (const float*)d_in[18];
    const float* lnw  = (const float*)d_in[19];
    const float* lnb  = (const float*)d_in[20];
    const float* wc2  = (const float*)d_in[21];
    const float* bc2  = (const float*)d_in[22];

    const int N = in_sizes[0] / 256;
    const int E = in_sizes[1] / 2;

    float* ws = (float*)d_ws;
    const size_t BIG = (size_t)N * 256;
    float* BUF0  = ws;                      // hs
    float* BUF1  = ws + BIG;                // t / activations
    float* dinv  = ws + 2 * BIG;            // N floats
    int*   deg   = (int*)(dinv + N);        // N ints
    int*   off   = deg + N;                 // N+1 ints
    int*   fill  = off + N + 1;             // N ints
    int*   csr   = fill + N;                // E ints
    float* cs1   = (float*)(csr + E);       // 256
    float* cs2   = cs1 + 256;
    float* meanv = cs2 + 256;
    float* istdv = meanv + 256;
    float* psum  = istdv + 256;             // 64
    float* pmax  = psum + 64;

    // degrees -> dinv, CSR build
    hipMemsetAsync(deg, 0, (size_t)N * sizeof(int), stream);
    hipMemsetAsync(fill, 0, (size_t)N * sizeof(int), stream);
    deg_kernel<<<1024, 256, 0, stream>>>(ei, deg, E);
    dinv_kernel<<<(N + 255) / 256, 256, 0, stream>>>(deg, dinv, N);
    scan_kernel<<<1, 1024, 0, stream>>>(deg, off, N);
    fill_kernel<<<1024, 256, 0, stream>>>(ei, off, fill, csr, E);

    struct Layer {
        const float *w, *b, *gw, *gb, *ga;
        int K, F, lf;
    } L[3] = {
        { w0, b0, gn0w, gn0b, gn0a, 256, 256, 8 },
        { w1, b1, gn1w, gn1b, gn1a, 256, 128, 7 },
        { w2, b2, gn2w, gn2b, gn2a, 128,  64, 6 },
    };
    const float* resb[3] = { x, nullptr, nullptr };

    // Every layer: GEMM cur->BUF0 (hs), gather BUF0->BUF1 (t), normgelu in-place BUF1.
    const float* cur = x;
    for (int li = 0; li < 3; ++li) {
        const int K = L[li].K, F = L[li].F, lf = L[li].lf;
        const long total = (long)N << lf;
        dim3 gg(F / 64, (N + 63) / 64);
        gemm_scale_kernel<<<gg, 256, 0, stream>>>(cur, L[li].w, dinv, BUF0, N, K, F);

        hipMemsetAsync(cs1, 0, 2 * 256 * sizeof(float), stream);
        if (F == 256) {
            int npb = 4, groups = (N + npb - 1) / npb;   // 5000
            gather_kernel<256><<<groups, 256, 0, stream>>>(BUF0, off, csr, dinv, L[li].b, BUF1, cs1, cs2, N);
        } else if (F == 128) {
            int npb = 8, groups = (N + npb - 1) / npb;   // 2500
            gather_kernel<128><<<groups, 256, 0, stream>>>(BUF0, off, csr, dinv, L[li].b, BUF1, cs1, cs2, N);
        } else {
            int npb = 16, groups = (N + npb - 1) / npb;  // 1250
            gather_kernel<64><<<groups, 256, 0, stream>>>(BUF0, off, csr, dinv, L[li].b, BUF1, cs1, cs2, N);
        }
        statfinal_kernel<<<1, F, 0, stream>>>(cs1, cs2, L[li].ga, meanv, istdv, N, F);

        long fb = (total + 255) / 256; if (fb > 4096) fb = 4096;
        normgelu_kernel<<<(int)fb, 256, 0, stream>>>(BUF1, meanv, istdv,
                                                     L[li].gw, L[li].gb, L[li].ga,
                                                     resb[li], BUF1, lf, total);
        cur = BUF1;
    }

    // pooling + head
    initpool_kernel<<<1, 64, 0, stream>>>(psum, pmax);
    colpool_kernel<<<(N + 127) / 128, 256, 0, stream>>>(cur, psum, pmax, N, 128);
    head_kernel<<<1, 64, 0, stream>>>(psum, pmax, wc1, bc1, lnw, lnb, wc2, bc2,
                                      (float*)d_out, N);
}

// Round 4
// 438.369 us; speedup vs baseline: 2.6587x; 2.6587x over previous
//
#include <hip/hip_runtime.h>
#include <math.h>

#define EPSV 1e-5f
#define MAXB 2560   // max gather blocks (partial-stat slots)

__device__ __forceinline__ float gelu_f(float x) {
    return 0.5f * x * (1.0f + erff(x * 0.70710678118654752440f));
}

// ---------------- degree / dinv ----------------
__global__ void deg_kernel(const int* __restrict__ ei, int* __restrict__ deg, int E) {
    int stride = gridDim.x * blockDim.x;
    for (int e = blockIdx.x * blockDim.x + threadIdx.x; e < E; e += stride)
        atomicAdd(&deg[ei[E + e]], 1);   // dst occurrences
}

__global__ void dinv_kernel(const int* __restrict__ deg, float* __restrict__ dinv, int N) {
    int i = blockIdx.x * blockDim.x + threadIdx.x;
    if (i < N) dinv[i] = rsqrtf((float)(deg[i] + 1));  // +1 self loop
}

// ---------------- exclusive scan of deg -> off  (single block, 1024 threads) ----------------
__global__ __launch_bounds__(1024) void scan_kernel(const int* __restrict__ deg,
                                                    int* __restrict__ off, int N) {
    __shared__ int sh[1024];
    int t = threadIdx.x;
    int chunk = (N + 1023) >> 10;
    int b = t * chunk;
    int e = b + chunk; if (e > N) e = N;
    int s = 0;
    for (int i = b; i < e; ++i) s += deg[i];
    sh[t] = s;
    __syncthreads();
    for (int d = 1; d < 1024; d <<= 1) {
        int v = (t >= d) ? sh[t - d] : 0;
        __syncthreads();
        sh[t] += v;
        __syncthreads();
    }
    int run = (t > 0) ? sh[t - 1] : 0;
    for (int i = b; i < e; ++i) { off[i] = run; run += deg[i]; }
    if (t == 1023) off[N] = sh[1023];
}

// ---------------- CSR fill: csr[off[d] + rank] = src ----------------
__global__ void fill_kernel(const int* __restrict__ ei, const int* __restrict__ off,
                            int* __restrict__ fill, int* __restrict__ csr, int E) {
    int stride = gridDim.x * blockDim.x;
    for (int e = blockIdx.x * blockDim.x + threadIdx.x; e < E; e += stride) {
        int d = ei[E + e];
        int p = off[d] + atomicAdd(&fill[d], 1);
        csr[p] = ei[e];
    }
}

// ---------------- GEMM: C[i][c] = (sum_k A[i][k] W[k][c]) * dinv[i] ----------------
// 64x64 tile, BK=16, 256 threads, 4x4 micro-tile per thread.
__global__ __launch_bounds__(256) void gemm_scale_kernel(
    const float* __restrict__ A, const float* __restrict__ W,
    const float* __restrict__ dinv, float* __restrict__ C,
    int M, int K, int Nc)
{
    __shared__ float As[64][17];
    __shared__ float4 Ws4[16][16];
    const int tid = threadIdx.x;
    const int tx = tid & 15, ty = tid >> 4;
    const int row0 = blockIdx.y * 64, col0 = blockIdx.x * 64;
    float acc[4][4] = {};
    const int ar = tid >> 2, ac4 = (tid & 3) * 4;   // A-tile coords
    const int wr = tid >> 4, wc4 = (tid & 15) * 4;  // W-tile coords

    for (int kk = 0; kk < K; kk += 16) {
        float4 av = make_float4(0.f, 0.f, 0.f, 0.f);
        int grow = row0 + ar;
        if (grow < M) av = *(const float4*)(A + (long)grow * K + kk + ac4);
        As[ar][ac4 + 0] = av.x; As[ar][ac4 + 1] = av.y;
        As[ar][ac4 + 2] = av.z; As[ar][ac4 + 3] = av.w;
        Ws4[wr][tid & 15] = *(const float4*)(W + (long)(kk + wr) * Nc + col0 + wc4);
        __syncthreads();
#pragma unroll
        for (int k = 0; k < 16; ++k) {
            float4 b4 = Ws4[k][tx];
            float a0 = As[ty * 4 + 0][k];
            float a1 = As[ty * 4 + 1][k];
            float a2 = As[ty * 4 + 2][k];
            float a3 = As[ty * 4 + 3][k];
            acc[0][0] = fmaf(a0, b4.x, acc[0][0]); acc[0][1] = fmaf(a0, b4.y, acc[0][1]);
            acc[0][2] = fmaf(a0, b4.z, acc[0][2]); acc[0][3] = fmaf(a0, b4.w, acc[0][3]);
            acc[1][0] = fmaf(a1, b4.x, acc[1][0]); acc[1][1] = fmaf(a1, b4.y, acc[1][1]);
            acc[1][2] = fmaf(a1, b4.z, acc[1][2]); acc[1][3] = fmaf(a1, b4.w, acc[1][3]);
            acc[2][0] = fmaf(a2, b4.x, acc[2][0]); acc[2][1] = fmaf(a2, b4.y, acc[2][1]);
            acc[2][2] = fmaf(a2, b4.z, acc[2][2]); acc[2][3] = fmaf(a2, b4.w, acc[2][3]);
            acc[3][0] = fmaf(a3, b4.x, acc[3][0]); acc[3][1] = fmaf(a3, b4.y, acc[3][1]);
            acc[3][2] = fmaf(a3, b4.z, acc[3][2]); acc[3][3] = fmaf(a3, b4.w, acc[3][3]);
        }
        __syncthreads();
    }
#pragma unroll
    for (int i = 0; i < 4; ++i) {
        int grow = row0 + ty * 4 + i;
        if (grow < M) {
            float dv = dinv[grow];
            float4 o = make_float4(acc[i][0] * dv, acc[i][1] * dv, acc[i][2] * dv, acc[i][3] * dv);
            *(float4*)(C + (long)grow * Nc + col0 + tx * 4) = o;
        }
    }
}

// ---------------- gather: t[d] = dinv[d]*(hs[d] + sum_{s in CSR[d]} hs[s]) + b
//     4-way edge unroll; per-block column-stat partials (NO atomics) ----------------
template<int F>
__global__ __launch_bounds__(256) void gather_kernel(
    const float* __restrict__ hs, const int* __restrict__ off,
    const int* __restrict__ csr, const float* __restrict__ dinv,
    const float* __restrict__ bias, float* __restrict__ t,
    float* __restrict__ p1, float* __restrict__ p2, int N)
{
    constexpr int LPN = F / 4;        // float4 lanes per node row
    constexpr int NPB = 256 / LPN;    // node slots per block
    const int lane = threadIdx.x % LPN;
    const int slot = threadIdx.x / LPN;
    const float4* hs4 = (const float4*)hs;
    float4* t4 = (float4*)t;
    const float4 bv = ((const float4*)bias)[lane];

    float4 a1 = make_float4(0.f, 0.f, 0.f, 0.f);
    float4 a2 = make_float4(0.f, 0.f, 0.f, 0.f);

    for (int d = blockIdx.x * NPB + slot; d < N; d += gridDim.x * NPB) {
        float4 acc0 = hs4[(long)d * LPN + lane];   // self loop
        float4 acc1 = make_float4(0.f, 0.f, 0.f, 0.f);
        float4 acc2 = make_float4(0.f, 0.f, 0.f, 0.f);
        float4 acc3 = make_float4(0.f, 0.f, 0.f, 0.f);
        const int e0 = off[d], e1 = off[d + 1];
        int e = e0;
        for (; e + 4 <= e1; e += 4) {
            int s0 = csr[e + 0];
            int s1 = csr[e + 1];
            int s2 = csr[e + 2];
            int s3 = csr[e + 3];
            float4 v0 = hs4[(long)s0 * LPN + lane];
            float4 v1 = hs4[(long)s1 * LPN + lane];
            float4 v2 = hs4[(long)s2 * LPN + lane];
            float4 v3 = hs4[(long)s3 * LPN + lane];
            acc0.x += v0.x; acc0.y += v0.y; acc0.z += v0.z; acc0.w += v0.w;
            acc1.x += v1.x; acc1.y += v1.y; acc1.z += v1.z; acc1.w += v1.w;
            acc2.x += v2.x; acc2.y += v2.y; acc2.z += v2.z; acc2.w += v2.w;
            acc3.x += v3.x; acc3.y += v3.y; acc3.z += v3.z; acc3.w += v3.w;
        }
        for (; e < e1; ++e) {
            int s = csr[e];
            float4 v = hs4[(long)s * LPN + lane];
            acc0.x += v.x; acc0.y += v.y; acc0.z += v.z; acc0.w += v.w;
        }
        acc0.x += acc1.x + acc2.x + acc3.x;
        acc0.y += acc1.y + acc2.y + acc3.y;
        acc0.z += acc1.z + acc2.z + acc3.z;
        acc0.w += acc1.w + acc2.w + acc3.w;

        float dv = dinv[d];
        float4 o;
        o.x = fmaf(dv, acc0.x, bv.x);
        o.y = fmaf(dv, acc0.y, bv.y);
        o.z = fmaf(dv, acc0.z, bv.z);
        o.w = fmaf(dv, acc0.w, bv.w);
        t4[(long)d * LPN + lane] = o;
        a1.x += o.x; a1.y += o.y; a1.z += o.z; a1.w += o.w;
        a2.x += o.x * o.x; a2.y += o.y * o.y; a2.z += o.z * o.z; a2.w += o.w * o.w;
    }

    // reduce stats across node slots (same feature lane), plain store to partial slot
    __shared__ float red[8][256];
    red[0][threadIdx.x] = a1.x; red[1][threadIdx.x] = a1.y;
    red[2][threadIdx.x] = a1.z; red[3][threadIdx.x] = a1.w;
    red[4][threadIdx.x] = a2.x; red[5][threadIdx.x] = a2.y;
    red[6][threadIdx.x] = a2.z; red[7][threadIdx.x] = a2.w;
    __syncthreads();
    if (slot == 0) {
        float sum[8];
#pragma unroll
        for (int k = 0; k < 8; ++k) {
            float s = red[k][lane];
            for (int j = 1; j < NPB; ++j) s += red[k][j * LPN + lane];
            sum[k] = s;
        }
        float4 o1 = make_float4(sum[0], sum[1], sum[2], sum[3]);
        float4 o2 = make_float4(sum[4], sum[5], sum[6], sum[7]);
        ((float4*)p1)[(long)blockIdx.x * LPN + lane] = o1;
        ((float4*)p2)[(long)blockIdx.x * LPN + lane] = o2;
    }
}

// ---------------- reduce per-block partials -> meanv / istdv  (one block per 64 cols) ----------------
template<int F>
__global__ __launch_bounds__(256) void statreduce_kernel(
    const float* __restrict__ p1, const float* __restrict__ p2,
    const float* __restrict__ ga,
    float* __restrict__ meanv, float* __restrict__ istdv,
    int nb, int N)
{
    const int c0 = blockIdx.x * 64;          // first column of this block
    const int c4 = threadIdx.x & 15;         // float4 group within 64 cols
    const int rl = threadIdx.x >> 4;         // 0..15 row-lane
    constexpr int LDF4 = F / 4;
    const float4* p14 = (const float4*)p1;
    const float4* p24 = (const float4*)p2;
    const int cbase = c0 / 4 + c4;

    float4 a1 = make_float4(0.f, 0.f, 0.f, 0.f);
    float4 a2 = make_float4(0.f, 0.f, 0.f, 0.f);
    for (int r = rl; r < nb; r += 16) {
        float4 v1 = p14[(long)r * LDF4 + cbase];
        float4 v2 = p24[(long)r * LDF4 + cbase];
        a1.x += v1.x; a1.y += v1.y; a1.z += v1.z; a1.w += v1.w;
        a2.x += v2.x; a2.y += v2.y; a2.z += v2.z; a2.w += v2.w;
    }
    __shared__ float4 sh1[256], sh2[256];
    sh1[rl * 16 + c4] = a1;
    sh2[rl * 16 + c4] = a2;
    __syncthreads();
    if (threadIdx.x < 16) {
        float4 t1 = sh1[threadIdx.x];
        float4 t2 = sh2[threadIdx.x];
        for (int j = 1; j < 16; ++j) {
            float4 u1 = sh1[j * 16 + threadIdx.x];
            float4 u2 = sh2[j * 16 + threadIdx.x];
            t1.x += u1.x; t1.y += u1.y; t1.z += u1.z; t1.w += u1.w;
            t2.x += u2.x; t2.y += u2.y; t2.z += u2.z; t2.w += u2.w;
        }
        float s1a[4] = { t1.x, t1.y, t1.z, t1.w };
        float s2a[4] = { t2.x, t2.y, t2.z, t2.w };
#pragma unroll
        for (int k = 0; k < 4; ++k) {
            int c = c0 + threadIdx.x * 4 + k;
            float m = s1a[k] / (float)N;
            float a = ga[c];
            float var = s2a[k] / (float)N - 2.f * a * m * m + a * a * m * m;
            meanv[c] = m;
            istdv[c] = rsqrtf(var + EPSV);
        }
    }
}

// ---------------- graphnorm + gelu (+ residual) ----------------
__global__ __launch_bounds__(256) void normgelu_kernel(
    const float* __restrict__ t, const float* __restrict__ meanv,
    const float* __restrict__ istdv, const float* __restrict__ gw,
    const float* __restrict__ gb, const float* __restrict__ ga,
    const float* __restrict__ res, float* __restrict__ out,
    int log2f, long total)
{
    long stride = (long)gridDim.x * blockDim.x;
    int fmask = (1 << log2f) - 1;
    for (long idx = (long)blockIdx.x * blockDim.x + threadIdx.x; idx < total; idx += stride) {
        int c = (int)idx & fmask;
        float v = t[idx];
        float y = gw[c] * (v - ga[c] * meanv[c]) * istdv[c] + gb[c];
        y = gelu_f(y);
        if (res) y += res[idx];
        out[idx] = y;
    }
}

// ---------------- pooling (fout = 64) ----------------
__device__ __forceinline__ void atomicMaxFloat(float* addr, float val) {
    unsigned* ua = (unsigned*)addr;
    unsigned old = *ua;
    while (true) {
        float of = __uint_as_float(old);
        if (of >= val) break;
        unsigned assumed = old;
        old = atomicCAS(ua, assumed, __float_as_uint(val));
        if (old == assumed) break;
    }
}

__global__ void initpool_kernel(float* __restrict__ psum, float* __restrict__ pmax) {
    int t = threadIdx.x;
    psum[t] = 0.f;
    pmax[t] = -INFINITY;
}

__global__ __launch_bounds__(256) void colpool_kernel(
    const float* __restrict__ x, float* __restrict__ psum, float* __restrict__ pmax,
    int M, int rowsPerBlock)
{
    int c = threadIdx.x & 63;
    int rl = threadIdx.x >> 6;
    int r0 = blockIdx.x * rowsPerBlock;
    int rend = r0 + rowsPerBlock; if (rend > M) rend = M;
    float a1 = 0.f, am = -INFINITY;
    for (int r = r0 + rl; r < rend; r += 4) {
        float v = x[(long)r * 64 + c];
        a1 += v; am = fmaxf(am, v);
    }
    __shared__ float sh1[256], shm[256];
    sh1[threadIdx.x] = a1; shm[threadIdx.x] = am;
    __syncthreads();
    if (threadIdx.x < 64) {
        for (int j = 1; j < 4; ++j) {
            a1 += sh1[c + j * 64];
            am = fmaxf(am, shm[c + j * 64]);
        }
        atomicAdd(&psum[c], a1);
        atomicMaxFloat(&pmax[c], am);
    }
}

// ---------------- head: pooled -> linear -> layernorm -> gelu -> linear ----------------
__global__ void head_kernel(const float* __restrict__ psum, const float* __restrict__ pmax,
                            const float* __restrict__ wc1, const float* __restrict__ bc1,
                            const float* __restrict__ lnw, const float* __restrict__ lnb,
                            const float* __restrict__ wc2, const float* __restrict__ bc2,
                            float* __restrict__ out, int M)
{
    __shared__ float p[192];
    int t = threadIdx.x; // 64 threads = 1 wave
    float s = psum[t];
    p[t] = s / (float)M;
    p[64 + t] = pmax[t];
    p[128 + t] = s;
    __syncthreads();
    float h = bc1[t];
    for (int k = 0; k < 192; ++k) h = fmaf(p[k], wc1[k * 64 + t], h);
    float m = h;
    for (int off = 32; off > 0; off >>= 1) m += __shfl_xor(m, off);
    m *= (1.f / 64.f);
    float d = h - m;
    float v = d * d;
    for (int off = 32; off > 0; off >>= 1) v += __shfl_xor(v, off);
    v *= (1.f / 64.f);
    float y = d * rsqrtf(v + EPSV) * lnw[t] + lnb[t];
    y = gelu_f(y);
    float o0 = y * wc2[t * 2 + 0];
    float o1 = y * wc2[t * 2 + 1];
    for (int off = 32; off > 0; off >>= 1) {
        o0 += __shfl_xor(o0, off);
        o1 += __shfl_xor(o1, off);
    }
    if (t == 0) {
        out[0] = o0 + bc2[0];
        out[1] = o1 + bc2[1];
    }
}

extern "C" void kernel_launch(void* const* d_in, const int* in_sizes, int n_in,
                              void* d_out, int out_size, void* d_ws, size_t ws_size,
                              hipStream_t stream)
{
    const float* x    = (const float*)d_in[0];
    const int*   ei   = (const int*)d_in[1];
    const float* w0   = (const float*)d_in[2];
    const float* b0   = (const float*)d_in[3];
    const float* gn0w = (const float*)d_in[4];
    const float* gn0b = (const float*)d_in[5];
    const float* gn0a = (const float*)d_in[6];
    const float* w1   = (const float*)d_in[7];
    const float* b1   = (const float*)d_in[8];
    const float* gn1w = (const float*)d_in[9];
    const float* gn1b = (const float*)d_in[10];
    const float* gn1a = (const float*)d_in[11];
    const float* w2   = (const float*)d_in[12];
    const float* b2   = (const float*)d_in[13];
    const float* gn2w = (const float*)d_in[14];
    const float* gn2b = (const float*)d_in[15];
    const float* gn2a = (const float*)d_in[16];
    const float* wc1  = (const float*)d_in[17];
    const float* bc1  = (const float*)d_in[18];
    const float* lnw  = (const float*)d_in[19];
    const float* lnb  = (const float*)d_in[20];
    const float* wc2  = (const float*)d_in[21];
    const float* bc2  = (const float*)d_in[22];

    const int N = in_sizes[0] / 256;
    const int E = in_sizes[1] / 2;

    float* ws = (float*)d_ws;
    const size_t BIG = (size_t)N * 256;
    float* BUF0  = ws;                      // hs
    float* BUF1  = ws + BIG;                // t / activations
    float* dinv  = ws + 2 * BIG;            // N floats
    int*   deg   = (int*)(dinv + N);        // N ints
    int*   off   = deg + N;                 // N+1 ints
    int*   fill  = off + N + 1;             // N ints
    int*   csr   = fill + N;                // E ints
    float* p1    = (float*)(csr + E);       // MAXB*256 partial col sums
    float* p2    = p1 + (size_t)MAXB * 256; // MAXB*256 partial col sumsq
    float* meanv = p2 + (size_t)MAXB * 256; // 256
    float* istdv = meanv + 256;
    float* psum  = istdv + 256;             // 64
    float* pmax  = psum + 64;

    // degrees -> dinv, CSR build
    hipMemsetAsync(deg, 0, (size_t)N * sizeof(int), stream);
    hipMemsetAsync(fill, 0, (size_t)N * sizeof(int), stream);
    deg_kernel<<<1024, 256, 0, stream>>>(ei, deg, E);
    dinv_kernel<<<(N + 255) / 256, 256, 0, stream>>>(deg, dinv, N);
    scan_kernel<<<1, 1024, 0, stream>>>(deg, off, N);
    fill_kernel<<<1024, 256, 0, stream>>>(ei, off, fill, csr, E);

    struct Layer {
        const float *w, *b, *gw, *gb, *ga;
        int K, F, lf;
    } L[3] = {
        { w0, b0, gn0w, gn0b, gn0a, 256, 256, 8 },
        { w1, b1, gn1w, gn1b, gn1a, 256, 128, 7 },
        { w2, b2, gn2w, gn2b, gn2a, 128,  64, 6 },
    };
    const float* resb[3] = { x, nullptr, nullptr };

    // Every layer: GEMM cur->BUF0 (hs), gather BUF0->BUF1 (t), normgelu in-place BUF1.
    const float* cur = x;
    for (int li = 0; li < 3; ++li) {
        const int K = L[li].K, F = L[li].F, lf = L[li].lf;
        const long total = (long)N << lf;
        dim3 gg(F / 64, (N + 63) / 64);
        gemm_scale_kernel<<<gg, 256, 0, stream>>>(cur, L[li].w, dinv, BUF0, N, K, F);

        int nb;
        if (F == 256) {
            int npb = 4, groups = (N + npb - 1) / npb;
            nb = groups < MAXB ? groups : MAXB;
            gather_kernel<256><<<nb, 256, 0, stream>>>(BUF0, off, csr, dinv, L[li].b, BUF1, p1, p2, N);
            statreduce_kernel<256><<<4, 256, 0, stream>>>(p1, p2, L[li].ga, meanv, istdv, nb, N);
        } else if (F == 128) {
            int npb = 8, groups = (N + npb - 1) / npb;
            nb = groups < MAXB ? groups : MAXB;
            gather_kernel<128><<<nb, 256, 0, stream>>>(BUF0, off, csr, dinv, L[li].b, BUF1, p1, p2, N);
            statreduce_kernel<128><<<2, 256, 0, stream>>>(p1, p2, L[li].ga, meanv, istdv, nb, N);
        } else {
            int npb = 16, groups = (N + npb - 1) / npb;
            nb = groups < MAXB ? groups : MAXB;
            gather_kernel<64><<<nb, 256, 0, stream>>>(BUF0, off, csr, dinv, L[li].b, BUF1, p1, p2, N);
            statreduce_kernel<64><<<1, 256, 0, stream>>>(p1, p2, L[li].ga, meanv, istdv, nb, N);
        }

        long fb = (total + 255) / 256; if (fb > 4096) fb = 4096;
        normgelu_kernel<<<(int)fb, 256, 0, stream>>>(BUF1, meanv, istdv,
                                                     L[li].gw, L[li].gb, L[li].ga,
                                                     resb[li], BUF1, lf, total);
        cur = BUF1;
    }

    // pooling + head
    initpool_kernel<<<1, 64, 0, stream>>>(psum, pmax);
    colpool_kernel<<<(N + 127) / 128, 256, 0, stream>>>(cur, psum, pmax, N, 128);
    head_kernel<<<1, 64, 0, stream>>>(psum, pmax, wc1, bc1, lnw, lnb, wc2, bc2,
                                      (float*)d_out, N);
}

// Round 5
// 335.534 us; speedup vs baseline: 3.4736x; 1.3065x over previous
//
#include <hip/hip_runtime.h>
#include <math.h>

#define EPSV 1e-5f
#define MAXB 2560   // max gather blocks (partial-stat slots)

__device__ __forceinline__ float gelu_f(float x) {
    return 0.5f * x * (1.0f + erff(x * 0.70710678118654752440f));
}

// ---------------- degree / dinv ----------------
__global__ void deg_kernel(const int* __restrict__ ei, int* __restrict__ deg, int E) {
    int stride = gridDim.x * blockDim.x;
    for (int e = blockIdx.x * blockDim.x + threadIdx.x; e < E; e += stride)
        atomicAdd(&deg[ei[E + e]], 1);   // dst occurrences
}

__global__ void dinv_kernel(const int* __restrict__ deg, float* __restrict__ dinv, int N) {
    int i = blockIdx.x * blockDim.x + threadIdx.x;
    if (i < N) dinv[i] = rsqrtf((float)(deg[i] + 1));  // +1 self loop
}

// ---------------- exclusive scan of deg -> off  (single block, 1024 threads) ----------------
__global__ __launch_bounds__(1024) void scan_kernel(const int* __restrict__ deg,
                                                    int* __restrict__ off, int N) {
    __shared__ int sh[1024];
    int t = threadIdx.x;
    int chunk = (N + 1023) >> 10;
    int b = t * chunk;
    int e = b + chunk; if (e > N) e = N;
    int s = 0;
    for (int i = b; i < e; ++i) s += deg[i];
    sh[t] = s;
    __syncthreads();
    for (int d = 1; d < 1024; d <<= 1) {
        int v = (t >= d) ? sh[t - d] : 0;
        __syncthreads();
        sh[t] += v;
        __syncthreads();
    }
    int run = (t > 0) ? sh[t - 1] : 0;
    for (int i = b; i < e; ++i) { off[i] = run; run += deg[i]; }
    if (t == 1023) off[N] = sh[1023];
}

// ---------------- CSR fill: csr[off[d] + rank] = src ----------------
__global__ void fill_kernel(const int* __restrict__ ei, const int* __restrict__ off,
                            int* __restrict__ fill, int* __restrict__ csr, int E) {
    int stride = gridDim.x * blockDim.x;
    for (int e = blockIdx.x * blockDim.x + threadIdx.x; e < E; e += stride) {
        int d = ei[E + e];
        int p = off[d] + atomicAdd(&fill[d], 1);
        csr[p] = ei[e];
    }
}

// ---------------- GEMM: C[i][c] = (sum_k A[i][k] W[k][c]) * dinv[i] ----------------
// 64x64 tile, BK=16, 256 threads, 4x4 micro-tile per thread.
__global__ __launch_bounds__(256) void gemm_scale_kernel(
    const float* __restrict__ A, const float* __restrict__ W,
    const float* __restrict__ dinv, float* __restrict__ C,
    int M, int K, int Nc)
{
    __shared__ float As[64][17];
    __shared__ float4 Ws4[16][16];
    const int tid = threadIdx.x;
    const int tx = tid & 15, ty = tid >> 4;
    const int row0 = blockIdx.y * 64, col0 = blockIdx.x * 64;
    float acc[4][4] = {};
    const int ar = tid >> 2, ac4 = (tid & 3) * 4;   // A-tile coords
    const int wr = tid >> 4, wc4 = (tid & 15) * 4;  // W-tile coords

    for (int kk = 0; kk < K; kk += 16) {
        float4 av = make_float4(0.f, 0.f, 0.f, 0.f);
        int grow = row0 + ar;
        if (grow < M) av = *(const float4*)(A + (long)grow * K + kk + ac4);
        As[ar][ac4 + 0] = av.x; As[ar][ac4 + 1] = av.y;
        As[ar][ac4 + 2] = av.z; As[ar][ac4 + 3] = av.w;
        Ws4[wr][tid & 15] = *(const float4*)(W + (long)(kk + wr) * Nc + col0 + wc4);
        __syncthreads();
#pragma unroll
        for (int k = 0; k < 16; ++k) {
            float4 b4 = Ws4[k][tx];
            float a0 = As[ty * 4 + 0][k];
            float a1 = As[ty * 4 + 1][k];
            float a2 = As[ty * 4 + 2][k];
            float a3 = As[ty * 4 + 3][k];
            acc[0][0] = fmaf(a0, b4.x, acc[0][0]); acc[0][1] = fmaf(a0, b4.y, acc[0][1]);
            acc[0][2] = fmaf(a0, b4.z, acc[0][2]); acc[0][3] = fmaf(a0, b4.w, acc[0][3]);
            acc[1][0] = fmaf(a1, b4.x, acc[1][0]); acc[1][1] = fmaf(a1, b4.y, acc[1][1]);
            acc[1][2] = fmaf(a1, b4.z, acc[1][2]); acc[1][3] = fmaf(a1, b4.w, acc[1][3]);
            acc[2][0] = fmaf(a2, b4.x, acc[2][0]); acc[2][1] = fmaf(a2, b4.y, acc[2][1]);
            acc[2][2] = fmaf(a2, b4.z, acc[2][2]); acc[2][3] = fmaf(a2, b4.w, acc[2][3]);
            acc[3][0] = fmaf(a3, b4.x, acc[3][0]); acc[3][1] = fmaf(a3, b4.y, acc[3][1]);
            acc[3][2] = fmaf(a3, b4.z, acc[3][2]); acc[3][3] = fmaf(a3, b4.w, acc[3][3]);
        }
        __syncthreads();
    }
#pragma unroll
    for (int i = 0; i < 4; ++i) {
        int grow = row0 + ty * 4 + i;
        if (grow < M) {
            float dv = dinv[grow];
            float4 o = make_float4(acc[i][0] * dv, acc[i][1] * dv, acc[i][2] * dv, acc[i][3] * dv);
            *(float4*)(C + (long)grow * Nc + col0 + tx * 4) = o;
        }
    }
}

// ---------------- gather: t[d] = dinv[d]*(hs[d] + sum_{s in CSR[d]} hs[s]) + b
//     4-way edge unroll; per-block column-stat partials (transposed layout, NO atomics) ----------------
template<int F>
__global__ __launch_bounds__(256) void gather_kernel(
    const float* __restrict__ hs, const int* __restrict__ off,
    const int* __restrict__ csr, const float* __restrict__ dinv,
    const float* __restrict__ bias, float* __restrict__ t,
    float* __restrict__ p1, float* __restrict__ p2, int N)
{
    constexpr int LPN = F / 4;        // float4 lanes per node row
    constexpr int NPB = 256 / LPN;    // node slots per block
    const int lane = threadIdx.x % LPN;
    const int slot = threadIdx.x / LPN;
    const float4* hs4 = (const float4*)hs;
    float4* t4 = (float4*)t;
    const float4 bv = ((const float4*)bias)[lane];

    float4 a1 = make_float4(0.f, 0.f, 0.f, 0.f);
    float4 a2 = make_float4(0.f, 0.f, 0.f, 0.f);

    for (int d = blockIdx.x * NPB + slot; d < N; d += gridDim.x * NPB) {
        float4 acc0 = hs4[(long)d * LPN + lane];   // self loop
        float4 acc1 = make_float4(0.f, 0.f, 0.f, 0.f);
        float4 acc2 = make_float4(0.f, 0.f, 0.f, 0.f);
        float4 acc3 = make_float4(0.f, 0.f, 0.f, 0.f);
        const int e0 = off[d], e1 = off[d + 1];
        int e = e0;
        for (; e + 4 <= e1; e += 4) {
            int s0 = csr[e + 0];
            int s1 = csr[e + 1];
            int s2 = csr[e + 2];
            int s3 = csr[e + 3];
            float4 v0 = hs4[(long)s0 * LPN + lane];
            float4 v1 = hs4[(long)s1 * LPN + lane];
            float4 v2 = hs4[(long)s2 * LPN + lane];
            float4 v3 = hs4[(long)s3 * LPN + lane];
            acc0.x += v0.x; acc0.y += v0.y; acc0.z += v0.z; acc0.w += v0.w;
            acc1.x += v1.x; acc1.y += v1.y; acc1.z += v1.z; acc1.w += v1.w;
            acc2.x += v2.x; acc2.y += v2.y; acc2.z += v2.z; acc2.w += v2.w;
            acc3.x += v3.x; acc3.y += v3.y; acc3.z += v3.z; acc3.w += v3.w;
        }
        for (; e < e1; ++e) {
            int s = csr[e];
            float4 v = hs4[(long)s * LPN + lane];
            acc0.x += v.x; acc0.y += v.y; acc0.z += v.z; acc0.w += v.w;
        }
        acc0.x += acc1.x + acc2.x + acc3.x;
        acc0.y += acc1.y + acc2.y + acc3.y;
        acc0.z += acc1.z + acc2.z + acc3.z;
        acc0.w += acc1.w + acc2.w + acc3.w;

        float dv = dinv[d];
        float4 o;
        o.x = fmaf(dv, acc0.x, bv.x);
        o.y = fmaf(dv, acc0.y, bv.y);
        o.z = fmaf(dv, acc0.z, bv.z);
        o.w = fmaf(dv, acc0.w, bv.w);
        t4[(long)d * LPN + lane] = o;
        a1.x += o.x; a1.y += o.y; a1.z += o.z; a1.w += o.w;
        a2.x += o.x * o.x; a2.y += o.y * o.y; a2.z += o.z * o.z; a2.w += o.w * o.w;
    }

    // reduce stats across node slots (same feature lane), store transposed: p[col_group][block]
    __shared__ float red[8][256];
    red[0][threadIdx.x] = a1.x; red[1][threadIdx.x] = a1.y;
    red[2][threadIdx.x] = a1.z; red[3][threadIdx.x] = a1.w;
    red[4][threadIdx.x] = a2.x; red[5][threadIdx.x] = a2.y;
    red[6][threadIdx.x] = a2.z; red[7][threadIdx.x] = a2.w;
    __syncthreads();
    if (slot == 0) {
        float sum[8];
#pragma unroll
        for (int k = 0; k < 8; ++k) {
            float s = red[k][lane];
            for (int j = 1; j < NPB; ++j) s += red[k][j * LPN + lane];
            sum[k] = s;
        }
        float4 o1 = make_float4(sum[0], sum[1], sum[2], sum[3]);
        float4 o2 = make_float4(sum[4], sum[5], sum[6], sum[7]);
        ((float4*)p1)[(long)lane * MAXB + blockIdx.x] = o1;
        ((float4*)p2)[(long)lane * MAXB + blockIdx.x] = o2;
    }
}

// ---------------- reduce per-block partials -> meanv / istdv
//      grid = F/4 blocks, 256 threads each; contiguous per-column-group runs ----------------
__global__ __launch_bounds__(256) void statreduce_kernel(
    const float* __restrict__ p1, const float* __restrict__ p2,
    const float* __restrict__ ga,
    float* __restrict__ meanv, float* __restrict__ istdv,
    int nb, int N)
{
    const int c4 = blockIdx.x;
    const float4* p14 = (const float4*)p1 + (long)c4 * MAXB;
    const float4* p24 = (const float4*)p2 + (long)c4 * MAXB;
    float4 a1 = make_float4(0.f, 0.f, 0.f, 0.f);
    float4 a2 = make_float4(0.f, 0.f, 0.f, 0.f);
    for (int r = threadIdx.x; r < nb; r += 256) {
        float4 v1 = p14[r];
        float4 v2 = p24[r];
        a1.x += v1.x; a1.y += v1.y; a1.z += v1.z; a1.w += v1.w;
        a2.x += v2.x; a2.y += v2.y; a2.z += v2.z; a2.w += v2.w;
    }
#pragma unroll
    for (int offv = 32; offv > 0; offv >>= 1) {
        a1.x += __shfl_down(a1.x, offv); a1.y += __shfl_down(a1.y, offv);
        a1.z += __shfl_down(a1.z, offv); a1.w += __shfl_down(a1.w, offv);
        a2.x += __shfl_down(a2.x, offv); a2.y += __shfl_down(a2.y, offv);
        a2.z += __shfl_down(a2.z, offv); a2.w += __shfl_down(a2.w, offv);
    }
    __shared__ float4 sh1[4], sh2[4];
    const int wid = threadIdx.x >> 6;
    if ((threadIdx.x & 63) == 0) { sh1[wid] = a1; sh2[wid] = a2; }
    __syncthreads();
    if (threadIdx.x == 0) {
        float4 t1 = sh1[0], t2 = sh2[0];
        for (int j = 1; j < 4; ++j) {
            float4 u1 = sh1[j], u2 = sh2[j];
            t1.x += u1.x; t1.y += u1.y; t1.z += u1.z; t1.w += u1.w;
            t2.x += u2.x; t2.y += u2.y; t2.z += u2.z; t2.w += u2.w;
        }
        float s1a[4] = { t1.x, t1.y, t1.z, t1.w };
        float s2a[4] = { t2.x, t2.y, t2.z, t2.w };
#pragma unroll
        for (int k = 0; k < 4; ++k) {
            int c = c4 * 4 + k;
            float m = s1a[k] / (float)N;
            float a = ga[c];
            float var = s2a[k] / (float)N - 2.f * a * m * m + a * a * m * m;
            meanv[c] = m;
            istdv[c] = rsqrtf(var + EPSV);
        }
    }
}

// ---------------- graphnorm + gelu (+ residual) ----------------
__global__ __launch_bounds__(256) void normgelu_kernel(
    const float* __restrict__ t, const float* __restrict__ meanv,
    const float* __restrict__ istdv, const float* __restrict__ gw,
    const float* __restrict__ gb, const float* __restrict__ ga,
    const float* __restrict__ res, float* __restrict__ out,
    int log2f, long total)
{
    long stride = (long)gridDim.x * blockDim.x;
    int fmask = (1 << log2f) - 1;
    for (long idx = (long)blockIdx.x * blockDim.x + threadIdx.x; idx < total; idx += stride) {
        int c = (int)idx & fmask;
        float v = t[idx];
        float y = gw[c] * (v - ga[c] * meanv[c]) * istdv[c] + gb[c];
        y = gelu_f(y);
        if (res) y += res[idx];
        out[idx] = y;
    }
}

// ---------------- pooling (fout = 64) ----------------
__device__ __forceinline__ void atomicMaxFloat(float* addr, float val) {
    unsigned* ua = (unsigned*)addr;
    unsigned old = *ua;
    while (true) {
        float of = __uint_as_float(old);
        if (of >= val) break;
        unsigned assumed = old;
        old = atomicCAS(ua, assumed, __float_as_uint(val));
        if (old == assumed) break;
    }
}

__global__ void initpool_kernel(float* __restrict__ psum, float* __restrict__ pmax) {
    int t = threadIdx.x;
    psum[t] = 0.f;
    pmax[t] = -INFINITY;
}

__global__ __launch_bounds__(256) void colpool_kernel(
    const float* __restrict__ x, float* __restrict__ psum, float* __restrict__ pmax,
    int M, int rowsPerBlock)
{
    int c = threadIdx.x & 63;
    int rl = threadIdx.x >> 6;
    int r0 = blockIdx.x * rowsPerBlock;
    int rend = r0 + rowsPerBlock; if (rend > M) rend = M;
    float a1 = 0.f, am = -INFINITY;
    for (int r = r0 + rl; r < rend; r += 4) {
        float v = x[(long)r * 64 + c];
        a1 += v; am = fmaxf(am, v);
    }
    __shared__ float sh1[256], shm[256];
    sh1[threadIdx.x] = a1; shm[threadIdx.x] = am;
    __syncthreads();
    if (threadIdx.x < 64) {
        for (int j = 1; j < 4; ++j) {
            a1 += sh1[c + j * 64];
            am = fmaxf(am, shm[c + j * 64]);
        }
        atomicAdd(&psum[c], a1);
        atomicMaxFloat(&pmax[c], am);
    }
}

// ---------------- head: pooled -> linear -> layernorm -> gelu -> linear ----------------
__global__ void head_kernel(const float* __restrict__ psum, const float* __restrict__ pmax,
                            const float* __restrict__ wc1, const float* __restrict__ bc1,
                            const float* __restrict__ lnw, const float* __restrict__ lnb,
                            const float* __restrict__ wc2, const float* __restrict__ bc2,
                            float* __restrict__ out, int M)
{
    __shared__ float p[192];
    int t = threadIdx.x; // 64 threads = 1 wave
    float s = psum[t];
    p[t] = s / (float)M;
    p[64 + t] = pmax[t];
    p[128 + t] = s;
    __syncthreads();
    float h = bc1[t];
    for (int k = 0; k < 192; ++k) h = fmaf(p[k], wc1[k * 64 + t], h);
    float m = h;
    for (int off = 32; off > 0; off >>= 1) m += __shfl_xor(m, off);
    m *= (1.f / 64.f);
    float d = h - m;
    float v = d * d;
    for (int off = 32; off > 0; off >>= 1) v += __shfl_xor(v, off);
    v *= (1.f / 64.f);
    float y = d * rsqrtf(v + EPSV) * lnw[t] + lnb[t];
    y = gelu_f(y);
    float o0 = y * wc2[t * 2 + 0];
    float o1 = y * wc2[t * 2 + 1];
    for (int off = 32; off > 0; off >>= 1) {
        o0 += __shfl_xor(o0, off);
        o1 += __shfl_xor(o1, off);
    }
    if (t == 0) {
        out[0] = o0 + bc2[0];
        out[1] = o1 + bc2[1];
    }
}

extern "C" void kernel_launch(void* const* d_in, const int* in_sizes, int n_in,
                              void* d_out, int out_size, void* d_ws, size_t ws_size,
                              hipStream_t stream)
{
    const float* x    = (const float*)d_in[0];
    const int*   ei   = (const int*)d_in[1];
    const float* w0   = (const float*)d_in[2];
    const float* b0   = (const float*)d_in[3];
    const float* gn0w = (const float*)d_in[4];
    const float* gn0b = (const float*)d_in[5];
    const float* gn0a = (const float*)d_in[6];
    const float* w1   = (const float*)d_in[7];
    const float* b1   = (const float*)d_in[8];
    const float* gn1w = (const float*)d_in[9];
    const float* gn1b = (const float*)d_in[10];
    const float* gn1a = (const float*)d_in[11];
    const float* w2   = (const float*)d_in[12];
    const float* b2   = (const float*)d_in[13];
    const float* gn2w = (const float*)d_in[14];
    const float* gn2b = (const float*)d_in[15];
    const float* gn2a = (const float*)d_in[16];
    const float* wc1  = (const float*)d_in[17];
    const float* bc1  = (const float*)d_in[18];
    const float* lnw  = (const float*)d_in[19];
    const float* lnb  = (const float*)d_in[20];
    const float* wc2  = (const float*)d_in[21];
    const float* bc2  = (const float*)d_in[22];

    const int N = in_sizes[0] / 256;
    const int E = in_sizes[1] / 2;

    float* ws = (float*)d_ws;
    const size_t BIG = (size_t)N * 256;
    float* BUF0  = ws;                      // hs
    float* BUF1  = ws + BIG;                // t / activations
    float* dinv  = ws + 2 * BIG;            // N floats
    int*   deg   = (int*)(dinv + N);        // N ints
    int*   off   = deg + N;                 // N+1 ints
    int*   fill  = off + N + 1;             // N ints
    int*   csr   = fill + N;                // E ints
    float* p1    = (float*)(csr + E);       // [F/4][MAXB] float4 partial col sums
    float* p2    = p1 + (size_t)MAXB * 256; // [F/4][MAXB] float4 partial col sumsq
    float* meanv = p2 + (size_t)MAXB * 256; // 256
    float* istdv = meanv + 256;
    float* psum  = istdv + 256;             // 64
    float* pmax  = psum + 64;

    // degrees -> dinv, CSR build
    hipMemsetAsync(deg, 0, (size_t)N * sizeof(int), stream);
    hipMemsetAsync(fill, 0, (size_t)N * sizeof(int), stream);
    deg_kernel<<<1024, 256, 0, stream>>>(ei, deg, E);
    dinv_kernel<<<(N + 255) / 256, 256, 0, stream>>>(deg, dinv, N);
    scan_kernel<<<1, 1024, 0, stream>>>(deg, off, N);
    fill_kernel<<<1024, 256, 0, stream>>>(ei, off, fill, csr, E);

    struct Layer {
        const float *w, *b, *gw, *gb, *ga;
        int K, F, lf;
    } L[3] = {
        { w0, b0, gn0w, gn0b, gn0a, 256, 256, 8 },
        { w1, b1, gn1w, gn1b, gn1a, 256, 128, 7 },
        { w2, b2, gn2w, gn2b, gn2a, 128,  64, 6 },
    };
    const float* resb[3] = { x, nullptr, nullptr };

    // Every layer: GEMM cur->BUF0 (hs), gather BUF0->BUF1 (t), normgelu in-place BUF1.
    const float* cur = x;
    for (int li = 0; li < 3; ++li) {
        const int K = L[li].K, F = L[li].F, lf = L[li].lf;
        const long total = (long)N << lf;
        dim3 gg(F / 64, (N + 63) / 64);
        gemm_scale_kernel<<<gg, 256, 0, stream>>>(cur, L[li].w, dinv, BUF0, N, K, F);

        int nb;
        if (F == 256) {
            int npb = 4, groups = (N + npb - 1) / npb;
            nb = groups < MAXB ? groups : MAXB;
            gather_kernel<256><<<nb, 256, 0, stream>>>(BUF0, off, csr, dinv, L[li].b, BUF1, p1, p2, N);
        } else if (F == 128) {
            int npb = 8, groups = (N + npb - 1) / npb;
            nb = groups < MAXB ? groups : MAXB;
            gather_kernel<128><<<nb, 256, 0, stream>>>(BUF0, off, csr, dinv, L[li].b, BUF1, p1, p2, N);
        } else {
            int npb = 16, groups = (N + npb - 1) / npb;
            nb = groups < MAXB ? groups : MAXB;
            gather_kernel<64><<<nb, 256, 0, stream>>>(BUF0, off, csr, dinv, L[li].b, BUF1, p1, p2, N);
        }
        statreduce_kernel<<<F / 4, 256, 0, stream>>>(p1, p2, L[li].ga, meanv, istdv, nb, N);

        long fb = (total + 255) / 256; if (fb > 4096) fb = 4096;
        normgelu_kernel<<<(int)fb, 256, 0, stream>>>(BUF1, meanv, istdv,
                                                     L[li].gw, L[li].gb, L[li].ga,
                                                     resb[li], BUF1, lf, total);
        cur = BUF1;
    }

    // pooling + head
    initpool_kernel<<<1, 64, 0, stream>>>(psum, pmax);
    colpool_kernel<<<(N + 127) / 128, 256, 0, stream>>>(cur, psum, pmax, N, 128);
    head_kernel<<<1, 64, 0, stream>>>(psum, pmax, wc1, bc1, lnw, lnb, wc2, bc2,
                                      (float*)d_out, N);
}

// Round 6
// 333.368 us; speedup vs baseline: 3.4962x; 1.0065x over previous
//
#include <hip/hip_runtime.h>
#include <math.h>

#define EPSV 1e-5f
#define MAXB 2560   // max gather blocks (partial-stat slots)

__device__ __forceinline__ float gelu_f(float x) {
    return 0.5f * x * (1.0f + erff(x * 0.70710678118654752440f));
}

__device__ __forceinline__ float4 f4add(float4 a, float4 b) {
    return make_float4(a.x + b.x, a.y + b.y, a.z + b.z, a.w + b.w);
}

// ---------------- degree / dinv ----------------
__global__ void deg_kernel(const int* __restrict__ ei, int* __restrict__ deg, int E) {
    int stride = gridDim.x * blockDim.x;
    for (int e = blockIdx.x * blockDim.x + threadIdx.x; e < E; e += stride)
        atomicAdd(&deg[ei[E + e]], 1);   // dst occurrences
}

__global__ void dinv_kernel(const int* __restrict__ deg, float* __restrict__ dinv, int N) {
    int i = blockIdx.x * blockDim.x + threadIdx.x;
    if (i < N) dinv[i] = rsqrtf((float)(deg[i] + 1));  // +1 self loop
}

// ---------------- exclusive scan of deg -> off  (single block, 1024 threads) ----------------
__global__ __launch_bounds__(1024) void scan_kernel(const int* __restrict__ deg,
                                                    int* __restrict__ off, int N) {
    __shared__ int sh[1024];
    int t = threadIdx.x;
    int chunk = (N + 1023) >> 10;
    int b = t * chunk;
    int e = b + chunk; if (e > N) e = N;
    int s = 0;
    for (int i = b; i < e; ++i) s += deg[i];
    sh[t] = s;
    __syncthreads();
    for (int d = 1; d < 1024; d <<= 1) {
        int v = (t >= d) ? sh[t - d] : 0;
        __syncthreads();
        sh[t] += v;
        __syncthreads();
    }
    int run = (t > 0) ? sh[t - 1] : 0;
    for (int i = b; i < e; ++i) { off[i] = run; run += deg[i]; }
    if (t == 1023) off[N] = sh[1023];
}

// ---------------- CSR fill: csr[off[d] + rank] = src ----------------
__global__ void fill_kernel(const int* __restrict__ ei, const int* __restrict__ off,
                            int* __restrict__ fill, int* __restrict__ csr, int E) {
    int stride = gridDim.x * blockDim.x;
    for (int e = blockIdx.x * blockDim.x + threadIdx.x; e < E; e += stride) {
        int d = ei[E + e];
        int p = off[d] + atomicAdd(&fill[d], 1);
        csr[p] = ei[e];
    }
}

// ---------------- GEMM: C[i][c] = (sum_k A[i][k] W[k][c]) * dinv[i] ----------------
// 64x64 tile, BK=16, 256 threads, 4x4 micro-tile per thread.
__global__ __launch_bounds__(256) void gemm_scale_kernel(
    const float* __restrict__ A, const float* __restrict__ W,
    const float* __restrict__ dinv, float* __restrict__ C,
    int M, int K, int Nc)
{
    __shared__ float As[64][17];
    __shared__ float4 Ws4[16][16];
    const int tid = threadIdx.x;
    const int tx = tid & 15, ty = tid >> 4;
    const int row0 = blockIdx.y * 64, col0 = blockIdx.x * 64;
    float acc[4][4] = {};
    const int ar = tid >> 2, ac4 = (tid & 3) * 4;   // A-tile coords
    const int wr = tid >> 4, wc4 = (tid & 15) * 4;  // W-tile coords

    for (int kk = 0; kk < K; kk += 16) {
        float4 av = make_float4(0.f, 0.f, 0.f, 0.f);
        int grow = row0 + ar;
        if (grow < M) av = *(const float4*)(A + (long)grow * K + kk + ac4);
        As[ar][ac4 + 0] = av.x; As[ar][ac4 + 1] = av.y;
        As[ar][ac4 + 2] = av.z; As[ar][ac4 + 3] = av.w;
        Ws4[wr][tid & 15] = *(const float4*)(W + (long)(kk + wr) * Nc + col0 + wc4);
        __syncthreads();
#pragma unroll
        for (int k = 0; k < 16; ++k) {
            float4 b4 = Ws4[k][tx];
            float a0 = As[ty * 4 + 0][k];
            float a1 = As[ty * 4 + 1][k];
            float a2 = As[ty * 4 + 2][k];
            float a3 = As[ty * 4 + 3][k];
            acc[0][0] = fmaf(a0, b4.x, acc[0][0]); acc[0][1] = fmaf(a0, b4.y, acc[0][1]);
            acc[0][2] = fmaf(a0, b4.z, acc[0][2]); acc[0][3] = fmaf(a0, b4.w, acc[0][3]);
            acc[1][0] = fmaf(a1, b4.x, acc[1][0]); acc[1][1] = fmaf(a1, b4.y, acc[1][1]);
            acc[1][2] = fmaf(a1, b4.z, acc[1][2]); acc[1][3] = fmaf(a1, b4.w, acc[1][3]);
            acc[2][0] = fmaf(a2, b4.x, acc[2][0]); acc[2][1] = fmaf(a2, b4.y, acc[2][1]);
            acc[2][2] = fmaf(a2, b4.z, acc[2][2]); acc[2][3] = fmaf(a2, b4.w, acc[2][3]);
            acc[3][0] = fmaf(a3, b4.x, acc[3][0]); acc[3][1] = fmaf(a3, b4.y, acc[3][1]);
            acc[3][2] = fmaf(a3, b4.z, acc[3][2]); acc[3][3] = fmaf(a3, b4.w, acc[3][3]);
        }
        __syncthreads();
    }
#pragma unroll
    for (int i = 0; i < 4; ++i) {
        int grow = row0 + ty * 4 + i;
        if (grow < M) {
            float dv = dinv[grow];
            float4 o = make_float4(acc[i][0] * dv, acc[i][1] * dv, acc[i][2] * dv, acc[i][3] * dv);
            *(float4*)(C + (long)grow * Nc + col0 + tx * 4) = o;
        }
    }
}

// ---------------- gather: t[d] = dinv[d]*(hs[d] + sum_{s in CSR[d]} hs[s]) + b
//     8-deep load batches (8 rows in flight per wave); per-block stat partials ----------------
template<int F>
__global__ __launch_bounds__(256) void gather_kernel(
    const float* __restrict__ hs, const int* __restrict__ off,
    const int* __restrict__ csr, const float* __restrict__ dinv,
    const float* __restrict__ bias, float* __restrict__ t,
    float* __restrict__ p1, float* __restrict__ p2, int N)
{
    constexpr int LPN = F / 4;        // float4 lanes per node row
    constexpr int NPB = 256 / LPN;    // node slots per block
    const int lane = threadIdx.x % LPN;
    const int slot = threadIdx.x / LPN;
    const float4* hs4 = (const float4*)hs;
    float4* t4 = (float4*)t;
    const float4 bv = ((const float4*)bias)[lane];

    float4 a1 = make_float4(0.f, 0.f, 0.f, 0.f);
    float4 a2 = make_float4(0.f, 0.f, 0.f, 0.f);

    for (int d = blockIdx.x * NPB + slot; d < N; d += gridDim.x * NPB) {
        float4 acc = hs4[(long)d * LPN + lane];   // self loop
        const int e0 = off[d], e1 = off[d + 1];
        int e = e0;
        // 8 independent row loads in flight, then pairwise-tree reduce
        for (; e + 8 <= e1; e += 8) {
            int s0 = csr[e + 0], s1 = csr[e + 1], s2 = csr[e + 2], s3 = csr[e + 3];
            int s4 = csr[e + 4], s5 = csr[e + 5], s6 = csr[e + 6], s7 = csr[e + 7];
            float4 v0 = hs4[(long)s0 * LPN + lane];
            float4 v1 = hs4[(long)s1 * LPN + lane];
            float4 v2 = hs4[(long)s2 * LPN + lane];
            float4 v3 = hs4[(long)s3 * LPN + lane];
            float4 v4 = hs4[(long)s4 * LPN + lane];
            float4 v5 = hs4[(long)s5 * LPN + lane];
            float4 v6 = hs4[(long)s6 * LPN + lane];
            float4 v7 = hs4[(long)s7 * LPN + lane];
            float4 u0 = f4add(v0, v1);
            float4 u1 = f4add(v2, v3);
            float4 u2 = f4add(v4, v5);
            float4 u3 = f4add(v6, v7);
            float4 w0 = f4add(u0, u1);
            float4 w1 = f4add(u2, u3);
            acc = f4add(acc, f4add(w0, w1));
        }
        for (; e + 2 <= e1; e += 2) {
            int s0 = csr[e + 0], s1 = csr[e + 1];
            float4 v0 = hs4[(long)s0 * LPN + lane];
            float4 v1 = hs4[(long)s1 * LPN + lane];
            acc = f4add(acc, f4add(v0, v1));
        }
        if (e < e1) {
            int s = csr[e];
            acc = f4add(acc, hs4[(long)s * LPN + lane]);
        }

        float dv = dinv[d];
        float4 o;
        o.x = fmaf(dv, acc.x, bv.x);
        o.y = fmaf(dv, acc.y, bv.y);
        o.z = fmaf(dv, acc.z, bv.z);
        o.w = fmaf(dv, acc.w, bv.w);
        t4[(long)d * LPN + lane] = o;
        a1.x += o.x; a1.y += o.y; a1.z += o.z; a1.w += o.w;
        a2.x += o.x * o.x; a2.y += o.y * o.y; a2.z += o.z * o.z; a2.w += o.w * o.w;
    }

    // reduce stats across node slots (same feature lane), store transposed: p[col_group][block]
    __shared__ float red[8][256];
    red[0][threadIdx.x] = a1.x; red[1][threadIdx.x] = a1.y;
    red[2][threadIdx.x] = a1.z; red[3][threadIdx.x] = a1.w;
    red[4][threadIdx.x] = a2.x; red[5][threadIdx.x] = a2.y;
    red[6][threadIdx.x] = a2.z; red[7][threadIdx.x] = a2.w;
    __syncthreads();
    if (slot == 0) {
        float sum[8];
#pragma unroll
        for (int k = 0; k < 8; ++k) {
            float s = red[k][lane];
            for (int j = 1; j < NPB; ++j) s += red[k][j * LPN + lane];
            sum[k] = s;
        }
        float4 o1 = make_float4(sum[0], sum[1], sum[2], sum[3]);
        float4 o2 = make_float4(sum[4], sum[5], sum[6], sum[7]);
        ((float4*)p1)[(long)lane * MAXB + blockIdx.x] = o1;
        ((float4*)p2)[(long)lane * MAXB + blockIdx.x] = o2;
    }
}

// ---------------- reduce per-block partials -> meanv / istdv
//      grid = F/4 blocks, 256 threads each; contiguous per-column-group runs ----------------
__global__ __launch_bounds__(256) void statreduce_kernel(
    const float* __restrict__ p1, const float* __restrict__ p2,
    const float* __restrict__ ga,
    float* __restrict__ meanv, float* __restrict__ istdv,
    int nb, int N)
{
    const int c4 = blockIdx.x;
    const float4* p14 = (const float4*)p1 + (long)c4 * MAXB;
    const float4* p24 = (const float4*)p2 + (long)c4 * MAXB;
    float4 a1 = make_float4(0.f, 0.f, 0.f, 0.f);
    float4 a2 = make_float4(0.f, 0.f, 0.f, 0.f);
    for (int r = threadIdx.x; r < nb; r += 256) {
        float4 v1 = p14[r];
        float4 v2 = p24[r];
        a1.x += v1.x; a1.y += v1.y; a1.z += v1.z; a1.w += v1.w;
        a2.x += v2.x; a2.y += v2.y; a2.z += v2.z; a2.w += v2.w;
    }
#pragma unroll
    for (int offv = 32; offv > 0; offv >>= 1) {
        a1.x += __shfl_down(a1.x, offv); a1.y += __shfl_down(a1.y, offv);
        a1.z += __shfl_down(a1.z, offv); a1.w += __shfl_down(a1.w, offv);
        a2.x += __shfl_down(a2.x, offv); a2.y += __shfl_down(a2.y, offv);
        a2.z += __shfl_down(a2.z, offv); a2.w += __shfl_down(a2.w, offv);
    }
    __shared__ float4 sh1[4], sh2[4];
    const int wid = threadIdx.x >> 6;
    if ((threadIdx.x & 63) == 0) { sh1[wid] = a1; sh2[wid] = a2; }
    __syncthreads();
    if (threadIdx.x == 0) {
        float4 t1 = sh1[0], t2 = sh2[0];
        for (int j = 1; j < 4; ++j) {
            float4 u1 = sh1[j], u2 = sh2[j];
            t1.x += u1.x; t1.y += u1.y; t1.z += u1.z; t1.w += u1.w;
            t2.x += u2.x; t2.y += u2.y; t2.z += u2.z; t2.w += u2.w;
        }
        float s1a[4] = { t1.x, t1.y, t1.z, t1.w };
        float s2a[4] = { t2.x, t2.y, t2.z, t2.w };
#pragma unroll
        for (int k = 0; k < 4; ++k) {
            int c = c4 * 4 + k;
            float m = s1a[k] / (float)N;
            float a = ga[c];
            float var = s2a[k] / (float)N - 2.f * a * m * m + a * a * m * m;
            meanv[c] = m;
            istdv[c] = rsqrtf(var + EPSV);
        }
    }
}

// ---------------- graphnorm + gelu (+ residual) ----------------
__global__ __launch_bounds__(256) void normgelu_kernel(
    const float* __restrict__ t, const float* __restrict__ meanv,
    const float* __restrict__ istdv, const float* __restrict__ gw,
    const float* __restrict__ gb, const float* __restrict__ ga,
    const float* __restrict__ res, float* __restrict__ out,
    int log2f, long total)
{
    long stride = (long)gridDim.x * blockDim.x;
    int fmask = (1 << log2f) - 1;
    for (long idx = (long)blockIdx.x * blockDim.x + threadIdx.x; idx < total; idx += stride) {
        int c = (int)idx & fmask;
        float v = t[idx];
        float y = gw[c] * (v - ga[c] * meanv[c]) * istdv[c] + gb[c];
        y = gelu_f(y);
        if (res) y += res[idx];
        out[idx] = y;
    }
}

// ---------------- pooling (fout = 64) ----------------
__device__ __forceinline__ void atomicMaxFloat(float* addr, float val) {
    unsigned* ua = (unsigned*)addr;
    unsigned old = *ua;
    while (true) {
        float of = __uint_as_float(old);
        if (of >= val) break;
        unsigned assumed = old;
        old = atomicCAS(ua, assumed, __float_as_uint(val));
        if (old == assumed) break;
    }
}

__global__ void initpool_kernel(float* __restrict__ psum, float* __restrict__ pmax) {
    int t = threadIdx.x;
    psum[t] = 0.f;
    pmax[t] = -INFINITY;
}

__global__ __launch_bounds__(256) void colpool_kernel(
    const float* __restrict__ x, float* __restrict__ psum, float* __restrict__ pmax,
    int M, int rowsPerBlock)
{
    int c = threadIdx.x & 63;
    int rl = threadIdx.x >> 6;
    int r0 = blockIdx.x * rowsPerBlock;
    int rend = r0 + rowsPerBlock; if (rend > M) rend = M;
    float a1 = 0.f, am = -INFINITY;
    for (int r = r0 + rl; r < rend; r += 4) {
        float v = x[(long)r * 64 + c];
        a1 += v; am = fmaxf(am, v);
    }
    __shared__ float sh1[256], shm[256];
    sh1[threadIdx.x] = a1; shm[threadIdx.x] = am;
    __syncthreads();
    if (threadIdx.x < 64) {
        for (int j = 1; j < 4; ++j) {
            a1 += sh1[c + j * 64];
            am = fmaxf(am, shm[c + j * 64]);
        }
        atomicAdd(&psum[c], a1);
        atomicMaxFloat(&pmax[c], am);
    }
}

// ---------------- head: pooled -> linear -> layernorm -> gelu -> linear ----------------
__global__ void head_kernel(const float* __restrict__ psum, const float* __restrict__ pmax,
                            const float* __restrict__ wc1, const float* __restrict__ bc1,
                            const float* __restrict__ lnw, const float* __restrict__ lnb,
                            const float* __restrict__ wc2, const float* __restrict__ bc2,
                            float* __restrict__ out, int M)
{
    __shared__ float p[192];
    int t = threadIdx.x; // 64 threads = 1 wave
    float s = psum[t];
    p[t] = s / (float)M;
    p[64 + t] = pmax[t];
    p[128 + t] = s;
    __syncthreads();
    float h = bc1[t];
    for (int k = 0; k < 192; ++k) h = fmaf(p[k], wc1[k * 64 + t], h);
    float m = h;
    for (int off = 32; off > 0; off >>= 1) m += __shfl_xor(m, off);
    m *= (1.f / 64.f);
    float d = h - m;
    float v = d * d;
    for (int off = 32; off > 0; off >>= 1) v += __shfl_xor(v, off);
    v *= (1.f / 64.f);
    float y = d * rsqrtf(v + EPSV) * lnw[t] + lnb[t];
    y = gelu_f(y);
    float o0 = y * wc2[t * 2 + 0];
    float o1 = y * wc2[t * 2 + 1];
    for (int off = 32; off > 0; off >>= 1) {
        o0 += __shfl_xor(o0, off);
        o1 += __shfl_xor(o1, off);
    }
    if (t == 0) {
        out[0] = o0 + bc2[0];
        out[1] = o1 + bc2[1];
    }
}

extern "C" void kernel_launch(void* const* d_in, const int* in_sizes, int n_in,
                              void* d_out, int out_size, void* d_ws, size_t ws_size,
                              hipStream_t stream)
{
    const float* x    = (const float*)d_in[0];
    const int*   ei   = (const int*)d_in[1];
    const float* w0   = (const float*)d_in[2];
    const float* b0   = (const float*)d_in[3];
    const float* gn0w = (const float*)d_in[4];
    const float* gn0b = (const float*)d_in[5];
    const float* gn0a = (const float*)d_in[6];
    const float* w1   = (const float*)d_in[7];
    const float* b1   = (const float*)d_in[8];
    const float* gn1w = (const float*)d_in[9];
    const float* gn1b = (const float*)d_in[10];
    const float* gn1a = (const float*)d_in[11];
    const float* w2   = (const float*)d_in[12];
    const float* b2   = (const float*)d_in[13];
    const float* gn2w = (const float*)d_in[14];
    const float* gn2b = (const float*)d_in[15];
    const float* gn2a = (const float*)d_in[16];
    const float* wc1  = (const float*)d_in[17];
    const float* bc1  = (const float*)d_in[18];
    const float* lnw  = (const float*)d_in[19];
    const float* lnb  = (const float*)d_in[20];
    const float* wc2  = (const float*)d_in[21];
    const float* bc2  = (const float*)d_in[22];

    const int N = in_sizes[0] / 256;
    const int E = in_sizes[1] / 2;

    float* ws = (float*)d_ws;
    const size_t BIG = (size_t)N * 256;
    float* BUF0  = ws;                      // hs
    float* BUF1  = ws + BIG;                // t / activations
    float* dinv  = ws + 2 * BIG;            // N floats
    int*   deg   = (int*)(dinv + N);        // N ints
    int*   off   = deg + N;                 // N+1 ints
    int*   fill  = off + N + 1;             // N ints
    int*   csr   = fill + N;                // E ints
    float* p1    = (float*)(csr + E);       // [F/4][MAXB] float4 partial col sums
    float* p2    = p1 + (size_t)MAXB * 256; // [F/4][MAXB] float4 partial col sumsq
    float* meanv = p2 + (size_t)MAXB * 256; // 256
    float* istdv = meanv + 256;
    float* psum  = istdv + 256;             // 64
    float* pmax  = psum + 64;

    // degrees -> dinv, CSR build
    hipMemsetAsync(deg, 0, (size_t)N * sizeof(int), stream);
    hipMemsetAsync(fill, 0, (size_t)N * sizeof(int), stream);
    deg_kernel<<<1024, 256, 0, stream>>>(ei, deg, E);
    dinv_kernel<<<(N + 255) / 256, 256, 0, stream>>>(deg, dinv, N);
    scan_kernel<<<1, 1024, 0, stream>>>(deg, off, N);
    fill_kernel<<<1024, 256, 0, stream>>>(ei, off, fill, csr, E);

    struct Layer {
        const float *w, *b, *gw, *gb, *ga;
        int K, F, lf;
    } L[3] = {
        { w0, b0, gn0w, gn0b, gn0a, 256, 256, 8 },
        { w1, b1, gn1w, gn1b, gn1a, 256, 128, 7 },
        { w2, b2, gn2w, gn2b, gn2a, 128,  64, 6 },
    };
    const float* resb[3] = { x, nullptr, nullptr };

    // Every layer: GEMM cur->BUF0 (hs), gather BUF0->BUF1 (t), normgelu in-place BUF1.
    const float* cur = x;
    for (int li = 0; li < 3; ++li) {
        const int K = L[li].K, F = L[li].F, lf = L[li].lf;
        const long total = (long)N << lf;
        dim3 gg(F / 64, (N + 63) / 64);
        gemm_scale_kernel<<<gg, 256, 0, stream>>>(cur, L[li].w, dinv, BUF0, N, K, F);

        int nb;
        if (F == 256) {
            int npb = 4, groups = (N + npb - 1) / npb;
            nb = groups < MAXB ? groups : MAXB;
            gather_kernel<256><<<nb, 256, 0, stream>>>(BUF0, off, csr, dinv, L[li].b, BUF1, p1, p2, N);
        } else if (F == 128) {
            int npb = 8, groups = (N + npb - 1) / npb;
            nb = groups < MAXB ? groups : MAXB;
            gather_kernel<128><<<nb, 256, 0, stream>>>(BUF0, off, csr, dinv, L[li].b, BUF1, p1, p2, N);
        } else {
            int npb = 16, groups = (N + npb - 1) / npb;
            nb = groups < MAXB ? groups : MAXB;
            gather_kernel<64><<<nb, 256, 0, stream>>>(BUF0, off, csr, dinv, L[li].b, BUF1, p1, p2, N);
        }
        statreduce_kernel<<<F / 4, 256, 0, stream>>>(p1, p2, L[li].ga, meanv, istdv, nb, N);

        long fb = (total + 255) / 256; if (fb > 4096) fb = 4096;
        normgelu_kernel<<<(int)fb, 256, 0, stream>>>(BUF1, meanv, istdv,
                                                     L[li].gw, L[li].gb, L[li].ga,
                                                     resb[li], BUF1, lf, total);
        cur = BUF1;
    }

    // pooling + head
    initpool_kernel<<<1, 64, 0, stream>>>(psum, pmax);
    colpool_kernel<<<(N + 127) / 128, 256, 0, stream>>>(cur, psum, pmax, N, 128);
    head_kernel<<<1, 64, 0, stream>>>(psum, pmax, wc1, bc1, lnw, lnb, wc2, bc2,
                                      (float*)d_out, N);
}

// Round 7
// 318.357 us; speedup vs baseline: 3.6610x; 1.0472x over previous
//
#include <hip/hip_runtime.h>
#include <math.h>

#define EPSV 1e-5f
#define MAXB 2560   // max gather blocks (partial-stat slots)
#define GBLK 2080   // gather grid (8 * 260), <= MAXB

__device__ __forceinline__ float gelu_f(float x) {
    return 0.5f * x * (1.0f + erff(x * 0.70710678118654752440f));
}

__device__ __forceinline__ float4 f4add(float4 a, float4 b) {
    return make_float4(a.x + b.x, a.y + b.y, a.z + b.z, a.w + b.w);
}

// ---------------- degree / dinv ----------------
__global__ void deg_kernel(const int* __restrict__ ei, int* __restrict__ deg, int E) {
    int stride = gridDim.x * blockDim.x;
    for (int e = blockIdx.x * blockDim.x + threadIdx.x; e < E; e += stride)
        atomicAdd(&deg[ei[E + e]], 1);   // dst occurrences
}

__global__ void dinv_kernel(const int* __restrict__ deg, float* __restrict__ dinv, int N) {
    int i = blockIdx.x * blockDim.x + threadIdx.x;
    if (i < N) dinv[i] = rsqrtf((float)(deg[i] + 1));  // +1 self loop
}

// ---------------- exclusive scan of deg -> off  (single block, 1024 threads) ----------------
__global__ __launch_bounds__(1024) void scan_kernel(const int* __restrict__ deg,
                                                    int* __restrict__ off, int N) {
    __shared__ int sh[1024];
    int t = threadIdx.x;
    int chunk = (N + 1023) >> 10;
    int b = t * chunk;
    int e = b + chunk; if (e > N) e = N;
    int s = 0;
    for (int i = b; i < e; ++i) s += deg[i];
    sh[t] = s;
    __syncthreads();
    for (int d = 1; d < 1024; d <<= 1) {
        int v = (t >= d) ? sh[t - d] : 0;
        __syncthreads();
        sh[t] += v;
        __syncthreads();
    }
    int run = (t > 0) ? sh[t - 1] : 0;
    for (int i = b; i < e; ++i) { off[i] = run; run += deg[i]; }
    if (t == 1023) off[N] = sh[1023];
}

// ---------------- CSR fill: csr[off[d] + rank] = src ----------------
__global__ void fill_kernel(const int* __restrict__ ei, const int* __restrict__ off,
                            int* __restrict__ fill, int* __restrict__ csr, int E) {
    int stride = gridDim.x * blockDim.x;
    for (int e = blockIdx.x * blockDim.x + threadIdx.x; e < E; e += stride) {
        int d = ei[E + e];
        int p = off[d] + atomicAdd(&fill[d], 1);
        csr[p] = ei[e];
    }
}

// ---------------- GEMM: C[i][c] = (sum_k A[i][k] W[k][c]) * dinv[i] ----------------
__global__ __launch_bounds__(256) void gemm_scale_kernel(
    const float* __restrict__ A, const float* __restrict__ W,
    const float* __restrict__ dinv, float* __restrict__ C,
    int M, int K, int Nc)
{
    __shared__ float As[64][17];
    __shared__ float4 Ws4[16][16];
    const int tid = threadIdx.x;
    const int tx = tid & 15, ty = tid >> 4;
    const int row0 = blockIdx.y * 64, col0 = blockIdx.x * 64;
    float acc[4][4] = {};
    const int ar = tid >> 2, ac4 = (tid & 3) * 4;   // A-tile coords
    const int wr = tid >> 4, wc4 = (tid & 15) * 4;  // W-tile coords

    for (int kk = 0; kk < K; kk += 16) {
        float4 av = make_float4(0.f, 0.f, 0.f, 0.f);
        int grow = row0 + ar;
        if (grow < M) av = *(const float4*)(A + (long)grow * K + kk + ac4);
        As[ar][ac4 + 0] = av.x; As[ar][ac4 + 1] = av.y;
        As[ar][ac4 + 2] = av.z; As[ar][ac4 + 3] = av.w;
        Ws4[wr][tid & 15] = *(const float4*)(W + (long)(kk + wr) * Nc + col0 + wc4);
        __syncthreads();
#pragma unroll
        for (int k = 0; k < 16; ++k) {
            float4 b4 = Ws4[k][tx];
            float a0 = As[ty * 4 + 0][k];
            float a1 = As[ty * 4 + 1][k];
            float a2 = As[ty * 4 + 2][k];
            float a3 = As[ty * 4 + 3][k];
            acc[0][0] = fmaf(a0, b4.x, acc[0][0]); acc[0][1] = fmaf(a0, b4.y, acc[0][1]);
            acc[0][2] = fmaf(a0, b4.z, acc[0][2]); acc[0][3] = fmaf(a0, b4.w, acc[0][3]);
            acc[1][0] = fmaf(a1, b4.x, acc[1][0]); acc[1][1] = fmaf(a1, b4.y, acc[1][1]);
            acc[1][2] = fmaf(a1, b4.z, acc[1][2]); acc[1][3] = fmaf(a1, b4.w, acc[1][3]);
            acc[2][0] = fmaf(a2, b4.x, acc[2][0]); acc[2][1] = fmaf(a2, b4.y, acc[2][1]);
            acc[2][2] = fmaf(a2, b4.z, acc[2][2]); acc[2][3] = fmaf(a2, b4.w, acc[2][3]);
            acc[3][0] = fmaf(a3, b4.x, acc[3][0]); acc[3][1] = fmaf(a3, b4.y, acc[3][1]);
            acc[3][2] = fmaf(a3, b4.z, acc[3][2]); acc[3][3] = fmaf(a3, b4.w, acc[3][3]);
        }
        __syncthreads();
    }
#pragma unroll
    for (int i = 0; i < 4; ++i) {
        int grow = row0 + ty * 4 + i;
        if (grow < M) {
            float dv = dinv[grow];
            float4 o = make_float4(acc[i][0] * dv, acc[i][1] * dv, acc[i][2] * dv, acc[i][3] * dv);
            *(float4*)(C + (long)grow * Nc + col0 + tx * 4) = o;
        }
    }
}

// ---------------- column-sliced gather ----------------
// Feature dim split into NG = F/64 groups of 64 cols. group = (blockIdx%8)%NG so
// each XCD (round-robin dispatch) touches ONE 20000x64 slice (~5 MB, L2-resident).
// 16 lanes per node (64 cols), NPB=16 nodes per block, 8-deep edge load batches.
template<int F>
__global__ __launch_bounds__(256) void gather_kernel(
    const float* __restrict__ hs, const int* __restrict__ off,
    const int* __restrict__ csr, const float* __restrict__ dinv,
    const float* __restrict__ bias, float* __restrict__ t,
    float* __restrict__ p1, float* __restrict__ p2, int N)
{
    constexpr int NG  = F / 64;       // column groups
    constexpr int LDR = F / 4;        // row stride in float4
    constexpr int NPB = 16;           // node slots per block
    const int lane = threadIdx.x & 15;
    const int slot = threadIdx.x >> 4;

    const int xs    = blockIdx.x & 7;           // XCD slot
    const int g     = xs % NG;                  // column group
    const int r     = xs / NG;                  // replica within group: 0..8/NG-1
    const int chunk = blockIdx.x >> 3;
    const int repl  = 8 / NG;
    const int nPerG = (int)(gridDim.x >> 3) * repl;   // node-blocks per group
    const int j     = chunk * repl + r;               // this block's node-block idx

    const int col4 = g * 16 + lane;             // float4 column index
    const float4* hs4 = (const float4*)hs;
    float4* t4 = (float4*)t;
    const float4 bv = ((const float4*)bias)[col4];

    float4 a1 = make_float4(0.f, 0.f, 0.f, 0.f);
    float4 a2 = make_float4(0.f, 0.f, 0.f, 0.f);

    for (int d = j * NPB + slot; d < N; d += nPerG * NPB) {
        float4 acc = hs4[(long)d * LDR + col4];   // self loop
        const int e0 = off[d], e1 = off[d + 1];
        int e = e0;
        for (; e + 8 <= e1; e += 8) {
            int s0 = csr[e + 0], s1 = csr[e + 1], s2 = csr[e + 2], s3 = csr[e + 3];
            int s4 = csr[e + 4], s5 = csr[e + 5], s6 = csr[e + 6], s7 = csr[e + 7];
            float4 v0 = hs4[(long)s0 * LDR + col4];
            float4 v1 = hs4[(long)s1 * LDR + col4];
            float4 v2 = hs4[(long)s2 * LDR + col4];
            float4 v3 = hs4[(long)s3 * LDR + col4];
            float4 v4 = hs4[(long)s4 * LDR + col4];
            float4 v5 = hs4[(long)s5 * LDR + col4];
            float4 v6 = hs4[(long)s6 * LDR + col4];
            float4 v7 = hs4[(long)s7 * LDR + col4];
            float4 u0 = f4add(v0, v1);
            float4 u1 = f4add(v2, v3);
            float4 u2 = f4add(v4, v5);
            float4 u3 = f4add(v6, v7);
            acc = f4add(acc, f4add(f4add(u0, u1), f4add(u2, u3)));
        }
        for (; e + 2 <= e1; e += 2) {
            int s0 = csr[e + 0], s1 = csr[e + 1];
            acc = f4add(acc, f4add(hs4[(long)s0 * LDR + col4], hs4[(long)s1 * LDR + col4]));
        }
        if (e < e1) {
            acc = f4add(acc, hs4[(long)csr[e] * LDR + col4]);
        }

        float dv = dinv[d];
        float4 o;
        o.x = fmaf(dv, acc.x, bv.x);
        o.y = fmaf(dv, acc.y, bv.y);
        o.z = fmaf(dv, acc.z, bv.z);
        o.w = fmaf(dv, acc.w, bv.w);
        t4[(long)d * LDR + col4] = o;
        a1.x += o.x; a1.y += o.y; a1.z += o.z; a1.w += o.w;
        a2.x += o.x * o.x; a2.y += o.y * o.y; a2.z += o.z * o.z; a2.w += o.w * o.w;
    }

    // reduce stats across the 16 node slots, write this block's partial (transposed layout)
    __shared__ float red[8][256];
    red[0][threadIdx.x] = a1.x; red[1][threadIdx.x] = a1.y;
    red[2][threadIdx.x] = a1.z; red[3][threadIdx.x] = a1.w;
    red[4][threadIdx.x] = a2.x; red[5][threadIdx.x] = a2.y;
    red[6][threadIdx.x] = a2.z; red[7][threadIdx.x] = a2.w;
    __syncthreads();
    if (slot == 0) {
        float sum[8];
#pragma unroll
        for (int k = 0; k < 8; ++k) {
            float s = red[k][lane];
            for (int jj = 1; jj < NPB; ++jj) s += red[k][jj * 16 + lane];
            sum[k] = s;
        }
        ((float4*)p1)[(long)col4 * MAXB + blockIdx.x] = make_float4(sum[0], sum[1], sum[2], sum[3]);
        ((float4*)p2)[(long)col4 * MAXB + blockIdx.x] = make_float4(sum[4], sum[5], sum[6], sum[7]);
    }
}

// ---------------- reduce per-block partials -> meanv / istdv ----------------
// Only blocks with (bid%8)%NG == colgroup wrote this column's partials.
__global__ __launch_bounds__(256) void statreduce_kernel(
    const float* __restrict__ p1, const float* __restrict__ p2,
    const float* __restrict__ ga,
    float* __restrict__ meanv, float* __restrict__ istdv,
    int nb, int N, int NG)
{
    const int c4 = blockIdx.x;
    const int g = (c4 >> 4) % NG;   // column group owning these 4 cols
    const float4* p14 = (const float4*)p1 + (long)c4 * MAXB;
    const float4* p24 = (const float4*)p2 + (long)c4 * MAXB;
    float4 a1 = make_float4(0.f, 0.f, 0.f, 0.f);
    float4 a2 = make_float4(0.f, 0.f, 0.f, 0.f);
    for (int r = threadIdx.x; r < nb; r += 256) {
        if (((r & 7) % NG) != g) continue;
        float4 v1 = p14[r];
        float4 v2 = p24[r];
        a1.x += v1.x; a1.y += v1.y; a1.z += v1.z; a1.w += v1.w;
        a2.x += v2.x; a2.y += v2.y; a2.z += v2.z; a2.w += v2.w;
    }
#pragma unroll
    for (int offv = 32; offv > 0; offv >>= 1) {
        a1.x += __shfl_down(a1.x, offv); a1.y += __shfl_down(a1.y, offv);
        a1.z += __shfl_down(a1.z, offv); a1.w += __shfl_down(a1.w, offv);
        a2.x += __shfl_down(a2.x, offv); a2.y += __shfl_down(a2.y, offv);
        a2.z += __shfl_down(a2.z, offv); a2.w += __shfl_down(a2.w, offv);
    }
    __shared__ float4 sh1[4], sh2[4];
    const int wid = threadIdx.x >> 6;
    if ((threadIdx.x & 63) == 0) { sh1[wid] = a1; sh2[wid] = a2; }
    __syncthreads();
    if (threadIdx.x == 0) {
        float4 t1 = sh1[0], t2 = sh2[0];
        for (int jj = 1; jj < 4; ++jj) {
            float4 u1 = sh1[jj], u2 = sh2[jj];
            t1.x += u1.x; t1.y += u1.y; t1.z += u1.z; t1.w += u1.w;
            t2.x += u2.x; t2.y += u2.y; t2.z += u2.z; t2.w += u2.w;
        }
        float s1a[4] = { t1.x, t1.y, t1.z, t1.w };
        float s2a[4] = { t2.x, t2.y, t2.z, t2.w };
#pragma unroll
        for (int k = 0; k < 4; ++k) {
            int c = c4 * 4 + k;
            float m = s1a[k] / (float)N;
            float a = ga[c];
            float var = s2a[k] / (float)N - 2.f * a * m * m + a * a * m * m;
            meanv[c] = m;
            istdv[c] = rsqrtf(var + EPSV);
        }
    }
}

// ---------------- graphnorm + gelu (+ residual) ----------------
__global__ __launch_bounds__(256) void normgelu_kernel(
    const float* __restrict__ t, const float* __restrict__ meanv,
    const float* __restrict__ istdv, const float* __restrict__ gw,
    const float* __restrict__ gb, const float* __restrict__ ga,
    const float* __restrict__ res, float* __restrict__ out,
    int log2f, long total)
{
    long stride = (long)gridDim.x * blockDim.x;
    int fmask = (1 << log2f) - 1;
    for (long idx = (long)blockIdx.x * blockDim.x + threadIdx.x; idx < total; idx += stride) {
        int c = (int)idx & fmask;
        float v = t[idx];
        float y = gw[c] * (v - ga[c] * meanv[c]) * istdv[c] + gb[c];
        y = gelu_f(y);
        if (res) y += res[idx];
        out[idx] = y;
    }
}

// ---------------- pooling (fout = 64) ----------------
__device__ __forceinline__ void atomicMaxFloat(float* addr, float val) {
    unsigned* ua = (unsigned*)addr;
    unsigned old = *ua;
    while (true) {
        float of = __uint_as_float(old);
        if (of >= val) break;
        unsigned assumed = old;
        old = atomicCAS(ua, assumed, __float_as_uint(val));
        if (old == assumed) break;
    }
}

__global__ void initpool_kernel(float* __restrict__ psum, float* __restrict__ pmax) {
    int t = threadIdx.x;
    psum[t] = 0.f;
    pmax[t] = -INFINITY;
}

__global__ __launch_bounds__(256) void colpool_kernel(
    const float* __restrict__ x, float* __restrict__ psum, float* __restrict__ pmax,
    int M, int rowsPerBlock)
{
    int c = threadIdx.x & 63;
    int rl = threadIdx.x >> 6;
    int r0 = blockIdx.x * rowsPerBlock;
    int rend = r0 + rowsPerBlock; if (rend > M) rend = M;
    float a1 = 0.f, am = -INFINITY;
    for (int r = r0 + rl; r < rend; r += 4) {
        float v = x[(long)r * 64 + c];
        a1 += v; am = fmaxf(am, v);
    }
    __shared__ float sh1[256], shm[256];
    sh1[threadIdx.x] = a1; shm[threadIdx.x] = am;
    __syncthreads();
    if (threadIdx.x < 64) {
        for (int j = 1; j < 4; ++j) {
            a1 += sh1[c + j * 64];
            am = fmaxf(am, shm[c + j * 64]);
        }
        atomicAdd(&psum[c], a1);
        atomicMaxFloat(&pmax[c], am);
    }
}

// ---------------- head: pooled -> linear -> layernorm -> gelu -> linear ----------------
__global__ void head_kernel(const float* __restrict__ psum, const float* __restrict__ pmax,
                            const float* __restrict__ wc1, const float* __restrict__ bc1,
                            const float* __restrict__ lnw, const float* __restrict__ lnb,
                            const float* __restrict__ wc2, const float* __restrict__ bc2,
                            float* __restrict__ out, int M)
{
    __shared__ float p[192];
    int t = threadIdx.x; // 64 threads = 1 wave
    float s = psum[t];
    p[t] = s / (float)M;
    p[64 + t] = pmax[t];
    p[128 + t] = s;
    __syncthreads();
    float h = bc1[t];
    for (int k = 0; k < 192; ++k) h = fmaf(p[k], wc1[k * 64 + t], h);
    float m = h;
    for (int off = 32; off > 0; off >>= 1) m += __shfl_xor(m, off);
    m *= (1.f / 64.f);
    float d = h - m;
    float v = d * d;
    for (int off = 32; off > 0; off >>= 1) v += __shfl_xor(v, off);
    v *= (1.f / 64.f);
    float y = d * rsqrtf(v + EPSV) * lnw[t] + lnb[t];
    y = gelu_f(y);
    float o0 = y * wc2[t * 2 + 0];
    float o1 = y * wc2[t * 2 + 1];
    for (int off = 32; off > 0; off >>= 1) {
        o0 += __shfl_xor(o0, off);
        o1 += __shfl_xor(o1, off);
    }
    if (t == 0) {
        out[0] = o0 + bc2[0];
        out[1] = o1 + bc2[1];
    }
}

extern "C" void kernel_launch(void* const* d_in, const int* in_sizes, int n_in,
                              void* d_out, int out_size, void* d_ws, size_t ws_size,
                              hipStream_t stream)
{
    const float* x    = (const float*)d_in[0];
    const int*   ei   = (const int*)d_in[1];
    const float* w0   = (const float*)d_in[2];
    const float* b0   = (const float*)d_in[3];
    const float* gn0w = (const float*)d_in[4];
    const float* gn0b = (const float*)d_in[5];
    const float* gn0a = (const float*)d_in[6];
    const float* w1   = (const float*)d_in[7];
    const float* b1   = (const float*)d_in[8];
    const float* gn1w = (const float*)d_in[9];
    const float* gn1b = (const float*)d_in[10];
    const float* gn1a = (const float*)d_in[11];
    const float* w2   = (const float*)d_in[12];
    const float* b2   = (const float*)d_in[13];
    const float* gn2w = (const float*)d_in[14];
    const float* gn2b = (const float*)d_in[15];
    const float* gn2a = (const float*)d_in[16];
    const float* wc1  = (const float*)d_in[17];
    const float* bc1  = (const float*)d_in[18];
    const float* lnw  = (const float*)d_in[19];
    const float* lnb  = (const float*)d_in[20];
    const float* wc2  = (const float*)d_in[21];
    const float* bc2  = (const float*)d_in[22];

    const int N = in_sizes[0] / 256;
    const int E = in_sizes[1] / 2;

    float* ws = (float*)d_ws;
    const size_t BIG = (size_t)N * 256;
    float* BUF0  = ws;                      // hs
    float* BUF1  = ws + BIG;                // t / activations
    float* dinv  = ws + 2 * BIG;            // N floats
    int*   deg   = (int*)(dinv + N);        // N ints
    int*   off   = deg + N;                 // N+1 ints
    int*   fill  = off + N + 1;             // N ints
    int*   csr   = fill + N;                // E ints
    float* p1    = (float*)(csr + E);       // [F/4][MAXB] float4 partial col sums
    float* p2    = p1 + (size_t)MAXB * 256; // [F/4][MAXB] float4 partial col sumsq
    float* meanv = p2 + (size_t)MAXB * 256; // 256
    float* istdv = meanv + 256;
    float* psum  = istdv + 256;             // 64
    float* pmax  = psum + 64;

    // degrees -> dinv, CSR build
    hipMemsetAsync(deg, 0, (size_t)N * sizeof(int), stream);
    hipMemsetAsync(fill, 0, (size_t)N * sizeof(int), stream);
    deg_kernel<<<1024, 256, 0, stream>>>(ei, deg, E);
    dinv_kernel<<<(N + 255) / 256, 256, 0, stream>>>(deg, dinv, N);
    scan_kernel<<<1, 1024, 0, stream>>>(deg, off, N);
    fill_kernel<<<1024, 256, 0, stream>>>(ei, off, fill, csr, E);

    struct Layer {
        const float *w, *b, *gw, *gb, *ga;
        int K, F, lf;
    } L[3] = {
        { w0, b0, gn0w, gn0b, gn0a, 256, 256, 8 },
        { w1, b1, gn1w, gn1b, gn1a, 256, 128, 7 },
        { w2, b2, gn2w, gn2b, gn2a, 128,  64, 6 },
    };
    const float* resb[3] = { x, nullptr, nullptr };

    // Every layer: GEMM cur->BUF0 (hs), gather BUF0->BUF1 (t), normgelu in-place BUF1.
    const float* cur = x;
    for (int li = 0; li < 3; ++li) {
        const int K = L[li].K, F = L[li].F, lf = L[li].lf;
        const long total = (long)N << lf;
        dim3 gg(F / 64, (N + 63) / 64);
        gemm_scale_kernel<<<gg, 256, 0, stream>>>(cur, L[li].w, dinv, BUF0, N, K, F);

        if (F == 256) {
            gather_kernel<256><<<GBLK, 256, 0, stream>>>(BUF0, off, csr, dinv, L[li].b, BUF1, p1, p2, N);
        } else if (F == 128) {
            gather_kernel<128><<<GBLK, 256, 0, stream>>>(BUF0, off, csr, dinv, L[li].b, BUF1, p1, p2, N);
        } else {
            gather_kernel<64><<<GBLK, 256, 0, stream>>>(BUF0, off, csr, dinv, L[li].b, BUF1, p1, p2, N);
        }
        statreduce_kernel<<<F / 4, 256, 0, stream>>>(p1, p2, L[li].ga, meanv, istdv, GBLK, N, F / 64);

        long fb = (total + 255) / 256; if (fb > 4096) fb = 4096;
        normgelu_kernel<<<(int)fb, 256, 0, stream>>>(BUF1, meanv, istdv,
                                                     L[li].gw, L[li].gb, L[li].ga,
                                                     resb[li], BUF1, lf, total);
        cur = BUF1;
    }

    // pooling + head
    initpool_kernel<<<1, 64, 0, stream>>>(psum, pmax);
    colpool_kernel<<<(N + 127) / 128, 256, 0, stream>>>(cur, psum, pmax, N, 128);
    head_kernel<<<1, 64, 0, stream>>>(psum, pmax, wc1, bc1, lnw, lnb, wc2, bc2,
                                      (float*)d_out, N);
}